// Round 1
// baseline (5891.353 us; speedup 1.0000x reference)
//
#include <hip/hip_runtime.h>
#include <hip/hip_bf16.h>

#define HID 128
#define NCLASS 10

// ---------------------------------------------------------------- degree/norm
__global__ void init_deg_kernel(float* deg, int N) {
    int i = blockIdx.x * 256 + threadIdx.x;
    if (i < N) deg[i] = 1.0f;  // self-loop
}

__global__ void count_deg_kernel(const int* __restrict__ dst, float* deg, int E) {
    int e = blockIdx.x * 256 + threadIdx.x;
    if (e < E) atomicAdd(&deg[dst[e]], 1.0f);
}

__global__ void rsqrt_kernel(float* deg, int N) {
    int i = blockIdx.x * 256 + threadIdx.x;
    if (i < N) deg[i] = rsqrtf(deg[i]);  // deg >= 1 always (self-loop)
}

// ---------------------------------------------------------------- GEMM (N x 128) @ (128 x 128), scaled by inv_sqrt[row]
// Block: 256 threads, 32 rows. LDS: W k-chunk 64x128 (32KB) + X tile 32x128 (16KB) = 48KB -> 3 blocks/CU.
// Thread (tx in [0,16): 8 cols, ty in [0,16): 2 rows) -> 16 outputs, 2048 FMA/thread.
__global__ __launch_bounds__(256) void gemm_scaled_kernel(
        const float* __restrict__ X, const float* __restrict__ W,
        const float* __restrict__ invs, float* __restrict__ H, int N) {
    __shared__ float Wl[64 * HID];   // 32 KB
    __shared__ float Xl[32 * HID];   // 16 KB
    const int t = threadIdx.x;
    const int row0 = blockIdx.x * 32;
    if (row0 >= N) return;

    // stage X tile (32 rows, coalesced float4)
    const float4* X4 = (const float4*)(X + (size_t)row0 * HID);
    float4* Xl4 = (float4*)Xl;
    for (int i = t; i < 32 * HID / 4; i += 256) Xl4[i] = X4[i];

    const int tx = t & 15;
    const int ty = t >> 4;
    const int c0 = tx * 8;
    float acc[2][8];
#pragma unroll
    for (int r = 0; r < 2; ++r)
#pragma unroll
        for (int c = 0; c < 8; ++c) acc[r][c] = 0.0f;

    for (int kk = 0; kk < HID; kk += 64) {
        __syncthreads();  // also covers Xl load on first iter / Wl reuse after
        const float4* W4 = (const float4*)(W + (size_t)kk * HID);
        float4* Wl4 = (float4*)Wl;
        for (int i = t; i < 64 * HID / 4; i += 256) Wl4[i] = W4[i];
        __syncthreads();
#pragma unroll 16
        for (int k = 0; k < 64; ++k) {
            const float x0 = Xl[(2 * ty + 0) * HID + kk + k];
            const float x1 = Xl[(2 * ty + 1) * HID + kk + k];
            const float4 wA = *(const float4*)&Wl[k * HID + c0];
            const float4 wB = *(const float4*)&Wl[k * HID + c0 + 4];
            acc[0][0] += x0 * wA.x; acc[0][1] += x0 * wA.y;
            acc[0][2] += x0 * wA.z; acc[0][3] += x0 * wA.w;
            acc[0][4] += x0 * wB.x; acc[0][5] += x0 * wB.y;
            acc[0][6] += x0 * wB.z; acc[0][7] += x0 * wB.w;
            acc[1][0] += x1 * wA.x; acc[1][1] += x1 * wA.y;
            acc[1][2] += x1 * wA.z; acc[1][3] += x1 * wA.w;
            acc[1][4] += x1 * wB.x; acc[1][5] += x1 * wB.y;
            acc[1][6] += x1 * wB.z; acc[1][7] += x1 * wB.w;
        }
    }

    const float s0 = invs[row0 + 2 * ty + 0];
    const float s1 = invs[row0 + 2 * ty + 1];
    float* H0 = H + (size_t)(row0 + 2 * ty + 0) * HID + c0;
    float* H1 = H + (size_t)(row0 + 2 * ty + 1) * HID + c0;
    float4 o;
    o.x = acc[0][0] * s0; o.y = acc[0][1] * s0; o.z = acc[0][2] * s0; o.w = acc[0][3] * s0;
    *(float4*)(H0 + 0) = o;
    o.x = acc[0][4] * s0; o.y = acc[0][5] * s0; o.z = acc[0][6] * s0; o.w = acc[0][7] * s0;
    *(float4*)(H0 + 4) = o;
    o.x = acc[1][0] * s1; o.y = acc[1][1] * s1; o.z = acc[1][2] * s1; o.w = acc[1][3] * s1;
    *(float4*)(H1 + 0) = o;
    o.x = acc[1][4] * s1; o.y = acc[1][5] * s1; o.z = acc[1][6] * s1; o.w = acc[1][7] * s1;
    *(float4*)(H1 + 4) = o;
}

// ---------------------------------------------------------------- edge scatter: AGG[dst] += HS[src]
// 32 threads per edge, float4 gather + 4 f32 atomics each.
__global__ void scatter_add_kernel(const int* __restrict__ src, const int* __restrict__ dst,
                                   const float* __restrict__ HS, float* __restrict__ AGG, int E) {
    const int tid = blockIdx.x * 256 + threadIdx.x;
    const int e = tid >> 5;
    if (e >= E) return;
    const int lane = tid & 31;
    const int s = src[e];
    const int d = dst[e];
    const float4 v = *(const float4*)&HS[(size_t)s * HID + lane * 4];
    float* out = &AGG[(size_t)d * HID + lane * 4];
    atomicAdd(out + 0, v.x);
    atomicAdd(out + 1, v.y);
    atomicAdd(out + 2, v.z);
    atomicAdd(out + 3, v.w);
}

// ---------------------------------------------------------------- x = relu(agg * inv_sqrt[row] + b)
__global__ void relu_bias_kernel(const float* __restrict__ AGG, const float* __restrict__ invs,
                                 const float* __restrict__ b, float* __restrict__ X, int n4) {
    const int idx = blockIdx.x * 256 + threadIdx.x;  // float4 index
    if (idx >= n4) return;
    const int row = idx >> 5;  // HID/4 = 32 float4 per row
    const float s = invs[row];
    const float4 a = ((const float4*)AGG)[idx];
    const float4 bb = ((const float4*)b)[idx & 31];
    float4 r;
    r.x = fmaxf(a.x * s + bb.x, 0.0f);
    r.y = fmaxf(a.y * s + bb.y, 0.0f);
    r.z = fmaxf(a.z * s + bb.z, 0.0f);
    r.w = fmaxf(a.w * s + bb.w, 0.0f);
    ((float4*)X)[idx] = r;
}

// ---------------------------------------------------------------- fused: out = relu(agg2*inv+b2) @ W_out + b_out
// One wave (64 lanes) per node; lane holds features 2*lane, 2*lane+1; shfl-reduce 10 outputs.
__global__ void out_gemm_kernel(const float* __restrict__ AGG, const float* __restrict__ invs,
                                const float* __restrict__ b2, const float* __restrict__ Wout,
                                const float* __restrict__ bout, float* __restrict__ OUT, int N) {
    const int gid = blockIdx.x * 256 + threadIdx.x;
    const int node = gid >> 6;
    if (node >= N) return;
    const int lane = threadIdx.x & 63;
    const float s = invs[node];
    const float2 a = *(const float2*)&AGG[(size_t)node * HID + lane * 2];
    const float v0 = fmaxf(a.x * s + b2[lane * 2 + 0], 0.0f);
    const float v1 = fmaxf(a.y * s + b2[lane * 2 + 1], 0.0f);
    const float* w0 = &Wout[(lane * 2 + 0) * NCLASS];
    const float* w1 = &Wout[(lane * 2 + 1) * NCLASS];
#pragma unroll
    for (int c = 0; c < NCLASS; ++c) {
        float p = v0 * w0[c] + v1 * w1[c];
#pragma unroll
        for (int off = 32; off > 0; off >>= 1) p += __shfl_down(p, off);
        if (lane == 0) OUT[(size_t)node * NCLASS + c] = p + bout[c];
    }
}

// ---------------------------------------------------------------- launch
extern "C" void kernel_launch(void* const* d_in, const int* in_sizes, int n_in,
                              void* d_out, int out_size, void* d_ws, size_t ws_size,
                              hipStream_t stream) {
    const int* ei        = (const int*)d_in[0];
    const float* emb     = (const float*)d_in[1];
    const float* W1      = (const float*)d_in[2];
    const float* b1      = (const float*)d_in[3];
    const float* W2      = (const float*)d_in[4];
    const float* b2      = (const float*)d_in[5];
    const float* Wout    = (const float*)d_in[6];
    const float* bout    = (const float*)d_in[7];
    float* out           = (float*)d_out;

    const int E = in_sizes[0] / 2;
    const int N = in_sizes[1] / HID;
    const int* src = ei;
    const int* dst = ei + E;

    // workspace layout (4KB-aligned chunks)
    char* ws = (char*)d_ws;
    const size_t feat_bytes = (size_t)N * HID * sizeof(float);  // 51.2 MB
    float* invs = (float*)ws;                                   // N floats
    size_t off = ((size_t)N * sizeof(float) + 4095) & ~(size_t)4095;
    float* bufA = (float*)(ws + off);
    float* bufB = (float*)(ws + off + feat_bytes);
    (void)ws_size; (void)n_in; (void)out_size;

    const int n4 = N * HID / 4;

    // degrees -> inv_sqrt (invs buffer)
    init_deg_kernel<<<(N + 255) / 256, 256, 0, stream>>>(invs, N);
    count_deg_kernel<<<(E + 255) / 256, 256, 0, stream>>>(dst, invs, E);
    rsqrt_kernel<<<(N + 255) / 256, 256, 0, stream>>>(invs, N);

    // ---- layer 1: hs1 = (emb @ W1) * inv  -> bufA
    gemm_scaled_kernel<<<(N + 31) / 32, 256, 0, stream>>>(emb, W1, invs, bufA, N);
    // agg1 init with self-loop contribution (hs1), then edge scatter
    hipMemcpyAsync(bufB, bufA, feat_bytes, hipMemcpyDeviceToDevice, stream);
    scatter_add_kernel<<<((size_t)E * 32 + 255) / 256, 256, 0, stream>>>(src, dst, bufA, bufB, E);
    // x1 = relu(agg1 * inv + b1) -> bufA
    relu_bias_kernel<<<(n4 + 255) / 256, 256, 0, stream>>>(bufB, invs, b1, bufA, n4);

    // ---- layer 2: hs2 = (x1 @ W2) * inv -> bufB
    gemm_scaled_kernel<<<(N + 31) / 32, 256, 0, stream>>>(bufA, W2, invs, bufB, N);
    hipMemcpyAsync(bufA, bufB, feat_bytes, hipMemcpyDeviceToDevice, stream);
    scatter_add_kernel<<<((size_t)E * 32 + 255) / 256, 256, 0, stream>>>(src, dst, bufB, bufA, E);

    // ---- fused relu+bias + output GEMM (128 -> 10)
    out_gemm_kernel<<<((size_t)N * 64 + 255) / 256, 256, 0, stream>>>(bufA, invs, b2, Wout, bout, out, N);
}

// Round 2
// 699.603 us; speedup vs baseline: 8.4210x; 8.4210x over previous
//
#include <hip/hip_runtime.h>
#include <hip/hip_bf16.h>

#define HID 128
#define NCLASS 10

// ================================================================ CSR build
__global__ void count_deg_kernel(const int* __restrict__ dst, int* deg, int E) {
    int e = blockIdx.x * 256 + threadIdx.x;
    if (e < E) atomicAdd(&deg[dst[e]], 1);
}

__global__ void invs_kernel(const int* __restrict__ deg, float* invs, int N) {
    int i = blockIdx.x * 256 + threadIdx.x;
    if (i < N) invs[i] = rsqrtf((float)deg[i] + 1.0f);  // +1 self-loop
}

// exclusive scan, 3-phase. Phase 1: 1024 elems/block (256 thr x 4).
__global__ __launch_bounds__(256) void scan1_kernel(const int* __restrict__ deg,
                                                    int* rp, int* bsum, int N) {
    __shared__ int sh[256];
    const int t = threadIdx.x;
    const int idx0 = blockIdx.x * 1024 + t * 4;
    int v[4];
#pragma unroll
    for (int j = 0; j < 4; ++j) v[j] = (idx0 + j < N) ? deg[idx0 + j] : 0;
    const int local = v[0] + v[1] + v[2] + v[3];
    sh[t] = local;
    __syncthreads();
    for (int off = 1; off < 256; off <<= 1) {
        int x = (t >= off) ? sh[t - off] : 0;
        __syncthreads();
        sh[t] += x;
        __syncthreads();
    }
    if (t == 255) bsum[blockIdx.x] = sh[255];
    int run = sh[t] - local;  // exclusive prefix of this thread's chunk
#pragma unroll
    for (int j = 0; j < 4; ++j) {
        if (idx0 + j < N) rp[idx0 + j] = run;
        run += v[j];
    }
}

// Phase 2: single block scans block sums (nb <= 128)
__global__ __launch_bounds__(128) void scan2_kernel(int* bsum, int nb) {
    __shared__ int sh[128];
    const int t = threadIdx.x;
    const int v = (t < nb) ? bsum[t] : 0;
    sh[t] = v;
    __syncthreads();
    for (int off = 1; off < 128; off <<= 1) {
        int x = (t >= off) ? sh[t - off] : 0;
        __syncthreads();
        sh[t] += x;
        __syncthreads();
    }
    if (t < nb) bsum[t] = sh[t] - v;  // exclusive
}

// Phase 3: add block offsets
__global__ void scan3_kernel(int* rp, const int* __restrict__ bsum, int N) {
    int i = blockIdx.x * 256 + threadIdx.x;
    if (i < N) rp[i] += bsum[i >> 10];
}

// fill: uses rp as cursor; afterwards rp[n] = end offset (start = rp[n]-deg[n])
__global__ void fill_kernel(const int* __restrict__ src, const int* __restrict__ dst,
                            int* rp, int* col, int E) {
    int e = blockIdx.x * 256 + threadIdx.x;
    if (e < E) {
        int p = atomicAdd(&rp[dst[e]], 1);
        col[p] = src[e];
    }
}

// ================================================================ GEMM (N x 128) @ (128 x 128), scaled by inv_sqrt[row]
__global__ __launch_bounds__(256) void gemm_scaled_kernel(
        const float* __restrict__ X, const float* __restrict__ W,
        const float* __restrict__ invs, float* __restrict__ H, int N) {
    __shared__ float Wl[64 * HID];   // 32 KB
    __shared__ float Xl[32 * HID];   // 16 KB
    const int t = threadIdx.x;
    const int row0 = blockIdx.x * 32;
    if (row0 >= N) return;

    const float4* X4 = (const float4*)(X + (size_t)row0 * HID);
    float4* Xl4 = (float4*)Xl;
    for (int i = t; i < 32 * HID / 4; i += 256) Xl4[i] = X4[i];

    const int tx = t & 15;
    const int ty = t >> 4;
    const int c0 = tx * 8;
    float acc[2][8];
#pragma unroll
    for (int r = 0; r < 2; ++r)
#pragma unroll
        for (int c = 0; c < 8; ++c) acc[r][c] = 0.0f;

    for (int kk = 0; kk < HID; kk += 64) {
        __syncthreads();
        const float4* W4 = (const float4*)(W + (size_t)kk * HID);
        float4* Wl4 = (float4*)Wl;
        for (int i = t; i < 64 * HID / 4; i += 256) Wl4[i] = W4[i];
        __syncthreads();
#pragma unroll 16
        for (int k = 0; k < 64; ++k) {
            const float x0 = Xl[(2 * ty + 0) * HID + kk + k];
            const float x1 = Xl[(2 * ty + 1) * HID + kk + k];
            const float4 wA = *(const float4*)&Wl[k * HID + c0];
            const float4 wB = *(const float4*)&Wl[k * HID + c0 + 4];
            acc[0][0] += x0 * wA.x; acc[0][1] += x0 * wA.y;
            acc[0][2] += x0 * wA.z; acc[0][3] += x0 * wA.w;
            acc[0][4] += x0 * wB.x; acc[0][5] += x0 * wB.y;
            acc[0][6] += x0 * wB.z; acc[0][7] += x0 * wB.w;
            acc[1][0] += x1 * wA.x; acc[1][1] += x1 * wA.y;
            acc[1][2] += x1 * wA.z; acc[1][3] += x1 * wA.w;
            acc[1][4] += x1 * wB.x; acc[1][5] += x1 * wB.y;
            acc[1][6] += x1 * wB.z; acc[1][7] += x1 * wB.w;
        }
    }

    const float s0 = invs[row0 + 2 * ty + 0];
    const float s1 = invs[row0 + 2 * ty + 1];
    float* H0 = H + (size_t)(row0 + 2 * ty + 0) * HID + c0;
    float* H1 = H + (size_t)(row0 + 2 * ty + 1) * HID + c0;
    float4 o;
    o.x = acc[0][0] * s0; o.y = acc[0][1] * s0; o.z = acc[0][2] * s0; o.w = acc[0][3] * s0;
    *(float4*)(H0 + 0) = o;
    o.x = acc[0][4] * s0; o.y = acc[0][5] * s0; o.z = acc[0][6] * s0; o.w = acc[0][7] * s0;
    *(float4*)(H0 + 4) = o;
    o.x = acc[1][0] * s1; o.y = acc[1][1] * s1; o.z = acc[1][2] * s1; o.w = acc[1][3] * s1;
    *(float4*)(H1 + 0) = o;
    o.x = acc[1][4] * s1; o.y = acc[1][5] * s1; o.z = acc[1][6] * s1; o.w = acc[1][7] * s1;
    *(float4*)(H1 + 4) = o;
}

// ================================================================ pull aggregation + relu(agg*inv + b)
// 32 lanes per node, lane holds 4 features (float4). 256 thr = 8 nodes/block.
__global__ __launch_bounds__(256) void pull_relu_kernel(
        const int* __restrict__ rp, const int* __restrict__ deg, const int* __restrict__ col,
        const float* __restrict__ HS, const float* __restrict__ invs,
        const float* __restrict__ b, float* __restrict__ X, int N) {
    const int node = (blockIdx.x * 256 + threadIdx.x) >> 5;
    if (node >= N) return;
    const int lane = threadIdx.x & 31;
    const int d = deg[node];
    const int start = rp[node] - d;  // rp holds end offset after fill

    float4 acc = *(const float4*)&HS[(size_t)node * HID + lane * 4];  // self-loop
    int i = 0;
    for (; i + 2 <= d; i += 2) {
        const int s0 = col[start + i];
        const int s1 = col[start + i + 1];
        const float4 v0 = *(const float4*)&HS[(size_t)s0 * HID + lane * 4];
        const float4 v1 = *(const float4*)&HS[(size_t)s1 * HID + lane * 4];
        acc.x += v0.x; acc.y += v0.y; acc.z += v0.z; acc.w += v0.w;
        acc.x += v1.x; acc.y += v1.y; acc.z += v1.z; acc.w += v1.w;
    }
    if (i < d) {
        const int s0 = col[start + i];
        const float4 v0 = *(const float4*)&HS[(size_t)s0 * HID + lane * 4];
        acc.x += v0.x; acc.y += v0.y; acc.z += v0.z; acc.w += v0.w;
    }
    const float sc = invs[node];
    const float4 bb = *(const float4*)&b[lane * 4];
    float4 r;
    r.x = fmaxf(acc.x * sc + bb.x, 0.0f);
    r.y = fmaxf(acc.y * sc + bb.y, 0.0f);
    r.z = fmaxf(acc.z * sc + bb.z, 0.0f);
    r.w = fmaxf(acc.w * sc + bb.w, 0.0f);
    *(float4*)&X[(size_t)node * HID + lane * 4] = r;
}

// ================================================================ pull + relu + output GEMM (128 -> 10), fused
__global__ __launch_bounds__(256) void pull_out_kernel(
        const int* __restrict__ rp, const int* __restrict__ deg, const int* __restrict__ col,
        const float* __restrict__ HS, const float* __restrict__ invs,
        const float* __restrict__ b2, const float* __restrict__ Wout,
        const float* __restrict__ bout, float* __restrict__ OUT, int N) {
    __shared__ float Wl[HID * NCLASS];  // 5 KB
    for (int i = threadIdx.x; i < HID * NCLASS; i += 256) Wl[i] = Wout[i];
    __syncthreads();

    const int node = (blockIdx.x * 256 + threadIdx.x) >> 5;
    if (node >= N) return;
    const int lane = threadIdx.x & 31;
    const int d = deg[node];
    const int start = rp[node] - d;

    float4 acc = *(const float4*)&HS[(size_t)node * HID + lane * 4];  // self-loop
    int i = 0;
    for (; i + 2 <= d; i += 2) {
        const int s0 = col[start + i];
        const int s1 = col[start + i + 1];
        const float4 v0 = *(const float4*)&HS[(size_t)s0 * HID + lane * 4];
        const float4 v1 = *(const float4*)&HS[(size_t)s1 * HID + lane * 4];
        acc.x += v0.x; acc.y += v0.y; acc.z += v0.z; acc.w += v0.w;
        acc.x += v1.x; acc.y += v1.y; acc.z += v1.z; acc.w += v1.w;
    }
    if (i < d) {
        const int s0 = col[start + i];
        const float4 v0 = *(const float4*)&HS[(size_t)s0 * HID + lane * 4];
        acc.x += v0.x; acc.y += v0.y; acc.z += v0.z; acc.w += v0.w;
    }
    const float sc = invs[node];
    const float4 bb = *(const float4*)&b2[lane * 4];
    float x0 = fmaxf(acc.x * sc + bb.x, 0.0f);
    float x1 = fmaxf(acc.y * sc + bb.y, 0.0f);
    float x2 = fmaxf(acc.z * sc + bb.z, 0.0f);
    float x3 = fmaxf(acc.w * sc + bb.w, 0.0f);

    const float* w0 = &Wl[(lane * 4 + 0) * NCLASS];
    float p[NCLASS];
#pragma unroll
    for (int c = 0; c < NCLASS; ++c)
        p[c] = x0 * w0[c] + x1 * w0[NCLASS + c] + x2 * w0[2 * NCLASS + c] + x3 * w0[3 * NCLASS + c];
#pragma unroll
    for (int c = 0; c < NCLASS; ++c) {
#pragma unroll
        for (int off = 16; off > 0; off >>= 1) p[c] += __shfl_xor(p[c], off, 32);
    }
#pragma unroll
    for (int c = 0; c < NCLASS; ++c) {
        const float r = p[c] + bout[c];
        if (lane == c) OUT[(size_t)node * NCLASS + c] = r;
    }
}

// ================================================================ launch
extern "C" void kernel_launch(void* const* d_in, const int* in_sizes, int n_in,
                              void* d_out, int out_size, void* d_ws, size_t ws_size,
                              hipStream_t stream) {
    const int* ei        = (const int*)d_in[0];
    const float* emb     = (const float*)d_in[1];
    const float* W1      = (const float*)d_in[2];
    const float* b1      = (const float*)d_in[3];
    const float* W2      = (const float*)d_in[4];
    const float* b2      = (const float*)d_in[5];
    const float* Wout    = (const float*)d_in[6];
    const float* bout    = (const float*)d_in[7];
    float* out           = (float*)d_out;

    const int E = in_sizes[0] / 2;
    const int N = in_sizes[1] / HID;
    const int* src = ei;
    const int* dst = ei + E;
    (void)ws_size; (void)n_in; (void)out_size;

    // workspace layout
    char* ws = (char*)d_ws;
    size_t off = 0;
    auto alloc = [&](size_t bytes) {
        void* p = ws + off;
        off = (off + bytes + 4095) & ~(size_t)4095;
        return p;
    };
    int*   deg  = (int*)alloc((size_t)N * 4);
    int*   rp   = (int*)alloc((size_t)N * 4);
    float* invs = (float*)alloc((size_t)N * 4);
    int*   bsum = (int*)alloc(128 * 4);
    int*   col  = (int*)alloc((size_t)E * 4);
    float* bufA = (float*)alloc((size_t)N * HID * 4);
    float* bufB = (float*)alloc((size_t)N * HID * 4);

    const int nb = (N + 1023) / 1024;  // scan phase-1 blocks (98)

    // ---- CSR build (group by dst) + norms
    hipMemsetAsync(deg, 0, (size_t)N * 4, stream);
    count_deg_kernel<<<(E + 255) / 256, 256, 0, stream>>>(dst, deg, E);
    invs_kernel<<<(N + 255) / 256, 256, 0, stream>>>(deg, invs, N);
    scan1_kernel<<<nb, 256, 0, stream>>>(deg, rp, bsum, N);
    scan2_kernel<<<1, 128, 0, stream>>>(bsum, nb);
    scan3_kernel<<<(N + 255) / 256, 256, 0, stream>>>(rp, bsum, N);
    fill_kernel<<<(E + 255) / 256, 256, 0, stream>>>(src, dst, rp, col, E);
    // after fill: rp[n] = end offset of node n's neighbor list

    // ---- layer 1: hs1 = (emb @ W1) * inv -> bufA ; x1 = relu(pull(hs1)*inv + b1) -> bufB
    gemm_scaled_kernel<<<(N + 31) / 32, 256, 0, stream>>>(emb, W1, invs, bufA, N);
    pull_relu_kernel<<<((size_t)N * 32 + 255) / 256, 256, 0, stream>>>(
        rp, deg, col, bufA, invs, b1, bufB, N);

    // ---- layer 2: hs2 = (x1 @ W2) * inv -> bufA ; out = relu(pull(hs2)*inv + b2) @ Wout + bout
    gemm_scaled_kernel<<<(N + 31) / 32, 256, 0, stream>>>(bufB, W2, invs, bufA, N);
    pull_out_kernel<<<((size_t)N * 32 + 255) / 256, 256, 0, stream>>>(
        rp, deg, col, bufA, invs, b2, Wout, bout, out, N);
}

// Round 3
// 617.210 us; speedup vs baseline: 9.5451x; 1.1335x over previous
//
#include <hip/hip_runtime.h>
#include <hip/hip_bf16.h>

#define HID 128
#define NCLASS 10

typedef unsigned int uint;

// ---- bf16 helpers (storage = ushort pairs packed in uint words) -------------
__device__ __forceinline__ uint bf16rne(float x) {
    uint u = __float_as_uint(x);
    return (u + 0x7FFFu + ((u >> 16) & 1u)) >> 16;
}
__device__ __forceinline__ uint pack2(float e0, float e1) {
    return bf16rne(e0) | (bf16rne(e1) << 16);
}
__device__ __forceinline__ void unpack2(uint w, float& lo, float& hi) {
    lo = __uint_as_float(w << 16);
    hi = __uint_as_float(w & 0xFFFF0000u);
}

// ================================================================ GEMM body
// (N x 128) @ (128 x 128) -> bf16 out. Block: 256 thr, 32 rows/block.
// LDS: Wl 64x128 (32KB) + Xl 32x128 (16KB). Thread: 2 rows x 8 cols.
__device__ __forceinline__ void gemm_body(const float* __restrict__ X,
                                          const float* __restrict__ W,
                                          uint* __restrict__ HS,  // bf16 out, 64 uints/row
                                          int N, int bidx, int t,
                                          float* Wl, float* Xl) {
    const int row0 = bidx * 32;

    const float4* X4 = (const float4*)(X + (size_t)row0 * HID);
    float4* Xl4 = (float4*)Xl;
    for (int i = t; i < 32 * HID / 4; i += 256) Xl4[i] = X4[i];

    const int tx = t & 15;
    const int ty = t >> 4;
    const int c0 = tx * 8;
    float acc[2][8];
#pragma unroll
    for (int r = 0; r < 2; ++r)
#pragma unroll
        for (int c = 0; c < 8; ++c) acc[r][c] = 0.0f;

    for (int kk = 0; kk < HID; kk += 64) {
        __syncthreads();
        const float4* W4 = (const float4*)(W + (size_t)kk * HID);
        float4* Wl4 = (float4*)Wl;
        for (int i = t; i < 64 * HID / 4; i += 256) Wl4[i] = W4[i];
        __syncthreads();
#pragma unroll 16
        for (int k = 0; k < 64; ++k) {
            const float x0 = Xl[(2 * ty + 0) * HID + kk + k];
            const float x1 = Xl[(2 * ty + 1) * HID + kk + k];
            const float4 wA = *(const float4*)&Wl[k * HID + c0];
            const float4 wB = *(const float4*)&Wl[k * HID + c0 + 4];
            acc[0][0] += x0 * wA.x; acc[0][1] += x0 * wA.y;
            acc[0][2] += x0 * wA.z; acc[0][3] += x0 * wA.w;
            acc[0][4] += x0 * wB.x; acc[0][5] += x0 * wB.y;
            acc[0][6] += x0 * wB.z; acc[0][7] += x0 * wB.w;
            acc[1][0] += x1 * wA.x; acc[1][1] += x1 * wA.y;
            acc[1][2] += x1 * wA.z; acc[1][3] += x1 * wA.w;
            acc[1][4] += x1 * wB.x; acc[1][5] += x1 * wB.y;
            acc[1][6] += x1 * wB.z; acc[1][7] += x1 * wB.w;
        }
    }

#pragma unroll
    for (int r = 0; r < 2; ++r) {
        uint4 o;
        o.x = pack2(acc[r][0], acc[r][1]);
        o.y = pack2(acc[r][2], acc[r][3]);
        o.z = pack2(acc[r][4], acc[r][5]);
        o.w = pack2(acc[r][6], acc[r][7]);
        *(uint4*)&HS[(size_t)(row0 + 2 * ty + r) * 64 + tx * 4] = o;
    }
}

// fat kernel: gemm1 (blocks < gemm_blocks) || degree count (remaining blocks)
__global__ __launch_bounds__(256) void gemm_count_kernel(
        const float* __restrict__ X, const float* __restrict__ W,
        uint* __restrict__ HS, int N,
        const int* __restrict__ dst, int* __restrict__ deg, int E, int gemm_blocks) {
    __shared__ float Wl[64 * HID];
    __shared__ float Xl[32 * HID];
    if ((int)blockIdx.x < gemm_blocks) {
        gemm_body(X, W, HS, N, blockIdx.x, threadIdx.x, Wl, Xl);
    } else {
        const int stride = (gridDim.x - gemm_blocks) * 256;
        for (int e = (blockIdx.x - gemm_blocks) * 256 + threadIdx.x; e < E; e += stride)
            atomicAdd(&deg[dst[e]], 1);
    }
}

__global__ __launch_bounds__(256) void gemm_kernel(
        const float* __restrict__ X, const float* __restrict__ W,
        uint* __restrict__ HS, int N) {
    __shared__ float Wl[64 * HID];
    __shared__ float Xl[32 * HID];
    gemm_body(X, W, HS, N, blockIdx.x, threadIdx.x, Wl, Xl);
}

// ================================================================ scan (CSR row pointers) + invs
__global__ __launch_bounds__(256) void scan1_kernel(const int* __restrict__ deg,
                                                    int* rp, int* bsum, float* invs, int N) {
    __shared__ int sh[256];
    const int t = threadIdx.x;
    const int idx0 = blockIdx.x * 1024 + t * 4;
    int v[4];
#pragma unroll
    for (int j = 0; j < 4; ++j) v[j] = (idx0 + j < N) ? deg[idx0 + j] : 0;
#pragma unroll
    for (int j = 0; j < 4; ++j)
        if (idx0 + j < N) invs[idx0 + j] = rsqrtf((float)v[j] + 1.0f);  // +1 self-loop
    const int local = v[0] + v[1] + v[2] + v[3];
    sh[t] = local;
    __syncthreads();
    for (int off = 1; off < 256; off <<= 1) {
        int x = (t >= off) ? sh[t - off] : 0;
        __syncthreads();
        sh[t] += x;
        __syncthreads();
    }
    if (t == 255) bsum[blockIdx.x] = sh[255];
    int run = sh[t] - local;
#pragma unroll
    for (int j = 0; j < 4; ++j) {
        if (idx0 + j < N) rp[idx0 + j] = run;
        run += v[j];
    }
}

__global__ __launch_bounds__(128) void scan2_kernel(int* bsum, int nb) {
    __shared__ int sh[128];
    const int t = threadIdx.x;
    const int v = (t < nb) ? bsum[t] : 0;
    sh[t] = v;
    __syncthreads();
    for (int off = 1; off < 128; off <<= 1) {
        int x = (t >= off) ? sh[t - off] : 0;
        __syncthreads();
        sh[t] += x;
        __syncthreads();
    }
    if (t < nb) bsum[t] = sh[t] - v;
}

__global__ void scan3_kernel(int* rp, const int* __restrict__ bsum, int N) {
    int i = blockIdx.x * 256 + threadIdx.x;
    if (i < N) rp[i] += bsum[i >> 10];
}

// fill: rp as cursor; afterwards rp[n] = end offset (start = rp[n]-deg[n])
__global__ void fill_kernel(const int* __restrict__ src, const int* __restrict__ dst,
                            int* rp, int* col, int E) {
    int e = blockIdx.x * 256 + threadIdx.x;
    if (e < E) {
        int p = atomicAdd(&rp[dst[e]], 1);
        col[p] = src[e];
    }
}

// ================================================================ pull (bf16 gather) + relu
// 16 lanes/node; lane holds 8 features (one uint4 = 8 bf16). agg includes
// per-src invs scale (moved out of GEMM); x = relu(agg*invs[n] + b) fp32.
__global__ __launch_bounds__(256) void pull_relu_kernel(
        const int* __restrict__ rp, const int* __restrict__ deg, const int* __restrict__ col,
        const uint* __restrict__ HS, const float* __restrict__ invs,
        const float* __restrict__ b, float* __restrict__ X, int N) {
    const int g = blockIdx.x * 256 + threadIdx.x;
    const int node = g >> 4;
    if (node >= N) return;
    const int lane = g & 15;
    const int d = deg[node];
    const int start = rp[node] - d;
    const uint4* H4 = (const uint4*)HS;  // 16 uint4 per row

    float acc[8];
    {
        const float sn = invs[node];
        uint4 u = H4[(size_t)node * 16 + lane];
        float f[8];
        unpack2(u.x, f[0], f[1]); unpack2(u.y, f[2], f[3]);
        unpack2(u.z, f[4], f[5]); unpack2(u.w, f[6], f[7]);
#pragma unroll
        for (int j = 0; j < 8; ++j) acc[j] = f[j] * sn;
    }
    int i = 0;
    for (; i + 2 <= d; i += 2) {
        const int s0 = col[start + i];
        const int s1 = col[start + i + 1];
        const float ss0 = invs[s0];
        const float ss1 = invs[s1];
        const uint4 u0 = H4[(size_t)s0 * 16 + lane];
        const uint4 u1 = H4[(size_t)s1 * 16 + lane];
        float f0[8], f1[8];
        unpack2(u0.x, f0[0], f0[1]); unpack2(u0.y, f0[2], f0[3]);
        unpack2(u0.z, f0[4], f0[5]); unpack2(u0.w, f0[6], f0[7]);
        unpack2(u1.x, f1[0], f1[1]); unpack2(u1.y, f1[2], f1[3]);
        unpack2(u1.z, f1[4], f1[5]); unpack2(u1.w, f1[6], f1[7]);
#pragma unroll
        for (int j = 0; j < 8; ++j) acc[j] += f0[j] * ss0;
#pragma unroll
        for (int j = 0; j < 8; ++j) acc[j] += f1[j] * ss1;
    }
    if (i < d) {
        const int s0 = col[start + i];
        const float ss0 = invs[s0];
        const uint4 u0 = H4[(size_t)s0 * 16 + lane];
        float f0[8];
        unpack2(u0.x, f0[0], f0[1]); unpack2(u0.y, f0[2], f0[3]);
        unpack2(u0.z, f0[4], f0[5]); unpack2(u0.w, f0[6], f0[7]);
#pragma unroll
        for (int j = 0; j < 8; ++j) acc[j] += f0[j] * ss0;
    }
    const float sn = invs[node];
    float x[8];
#pragma unroll
    for (int j = 0; j < 8; ++j) x[j] = fmaxf(acc[j] * sn + b[lane * 8 + j], 0.0f);
    float4* out = (float4*)&X[(size_t)node * HID + lane * 8];
    out[0] = make_float4(x[0], x[1], x[2], x[3]);
    out[1] = make_float4(x[4], x[5], x[6], x[7]);
}

// ================================================================ pull + relu + out-GEMM (128->10)
__global__ __launch_bounds__(256) void pull_out_kernel(
        const int* __restrict__ rp, const int* __restrict__ deg, const int* __restrict__ col,
        const uint* __restrict__ HS, const float* __restrict__ invs,
        const float* __restrict__ b2, const float* __restrict__ Wout,
        const float* __restrict__ bout, float* __restrict__ OUT, int N) {
    __shared__ float Wl[HID * 11];  // pitch 11: 4-way instead of 8-way conflicts
    for (int i = threadIdx.x; i < HID * NCLASS; i += 256)
        Wl[(i / NCLASS) * 11 + (i % NCLASS)] = Wout[i];
    __syncthreads();

    const int g = blockIdx.x * 256 + threadIdx.x;
    const int node = g >> 4;
    if (node >= N) return;
    const int lane = g & 15;
    const int d = deg[node];
    const int start = rp[node] - d;
    const uint4* H4 = (const uint4*)HS;

    float acc[8];
    {
        const float sn = invs[node];
        uint4 u = H4[(size_t)node * 16 + lane];
        float f[8];
        unpack2(u.x, f[0], f[1]); unpack2(u.y, f[2], f[3]);
        unpack2(u.z, f[4], f[5]); unpack2(u.w, f[6], f[7]);
#pragma unroll
        for (int j = 0; j < 8; ++j) acc[j] = f[j] * sn;
    }
    int i = 0;
    for (; i + 2 <= d; i += 2) {
        const int s0 = col[start + i];
        const int s1 = col[start + i + 1];
        const float ss0 = invs[s0];
        const float ss1 = invs[s1];
        const uint4 u0 = H4[(size_t)s0 * 16 + lane];
        const uint4 u1 = H4[(size_t)s1 * 16 + lane];
        float f0[8], f1[8];
        unpack2(u0.x, f0[0], f0[1]); unpack2(u0.y, f0[2], f0[3]);
        unpack2(u0.z, f0[4], f0[5]); unpack2(u0.w, f0[6], f0[7]);
        unpack2(u1.x, f1[0], f1[1]); unpack2(u1.y, f1[2], f1[3]);
        unpack2(u1.z, f1[4], f1[5]); unpack2(u1.w, f1[6], f1[7]);
#pragma unroll
        for (int j = 0; j < 8; ++j) acc[j] += f0[j] * ss0;
#pragma unroll
        for (int j = 0; j < 8; ++j) acc[j] += f1[j] * ss1;
    }
    if (i < d) {
        const int s0 = col[start + i];
        const float ss0 = invs[s0];
        const uint4 u0 = H4[(size_t)s0 * 16 + lane];
        float f0[8];
        unpack2(u0.x, f0[0], f0[1]); unpack2(u0.y, f0[2], f0[3]);
        unpack2(u0.z, f0[4], f0[5]); unpack2(u0.w, f0[6], f0[7]);
#pragma unroll
        for (int j = 0; j < 8; ++j) acc[j] += f0[j] * ss0;
    }
    const float sn = invs[node];
    float x[8];
#pragma unroll
    for (int j = 0; j < 8; ++j) x[j] = fmaxf(acc[j] * sn + b2[lane * 8 + j], 0.0f);

    float p[NCLASS];
#pragma unroll
    for (int c = 0; c < NCLASS; ++c) {
        float s = 0.0f;
#pragma unroll
        for (int j = 0; j < 8; ++j) s += x[j] * Wl[(lane * 8 + j) * 11 + c];
        p[c] = s;
    }
#pragma unroll
    for (int c = 0; c < NCLASS; ++c) {
#pragma unroll
        for (int off = 8; off > 0; off >>= 1) p[c] += __shfl_xor(p[c], off, 16);
    }
    if (lane < NCLASS) OUT[(size_t)node * NCLASS + lane] = p[lane] + bout[lane];
}

// ================================================================ launch
extern "C" void kernel_launch(void* const* d_in, const int* in_sizes, int n_in,
                              void* d_out, int out_size, void* d_ws, size_t ws_size,
                              hipStream_t stream) {
    const int* ei        = (const int*)d_in[0];
    const float* emb     = (const float*)d_in[1];
    const float* W1      = (const float*)d_in[2];
    const float* b1      = (const float*)d_in[3];
    const float* W2      = (const float*)d_in[4];
    const float* b2      = (const float*)d_in[5];
    const float* Wout    = (const float*)d_in[6];
    const float* bout    = (const float*)d_in[7];
    float* out           = (float*)d_out;

    const int E = in_sizes[0] / 2;
    const int N = in_sizes[1] / HID;
    const int* src = ei;
    const int* dst = ei + E;
    (void)ws_size; (void)n_in; (void)out_size;

    char* ws = (char*)d_ws;
    size_t off = 0;
    auto alloc = [&](size_t bytes) {
        void* p = ws + off;
        off = (off + bytes + 4095) & ~(size_t)4095;
        return p;
    };
    int*   deg  = (int*)alloc((size_t)N * 4);
    int*   rp   = (int*)alloc((size_t)N * 4);
    float* invs = (float*)alloc((size_t)N * 4);
    int*   bsum = (int*)alloc(128 * 4);
    int*   col  = (int*)alloc((size_t)E * 4);
    uint*  HS   = (uint*)alloc((size_t)N * HID * 2);   // bf16 features (reused by both layers)
    float* X1   = (float*)alloc((size_t)N * HID * 4);  // fp32 hidden

    const int nb = (N + 1023) / 1024;         // 98
    const int gemm_blocks = (N + 31) / 32;    // 3125
    const int count_blocks = 512;

    hipMemsetAsync(deg, 0, (size_t)N * 4, stream);
    // gemm1 (emb@W1 -> HS bf16, no scale) || degree count
    gemm_count_kernel<<<gemm_blocks + count_blocks, 256, 0, stream>>>(
        emb, W1, HS, N, dst, deg, E, gemm_blocks);
    scan1_kernel<<<nb, 256, 0, stream>>>(deg, rp, bsum, invs, N);
    scan2_kernel<<<1, 128, 0, stream>>>(bsum, nb);
    scan3_kernel<<<(N + 255) / 256, 256, 0, stream>>>(rp, bsum, N);
    fill_kernel<<<(E + 255) / 256, 256, 0, stream>>>(src, dst, rp, col, E);

    // layer 1 aggregate: x1 = relu(pull(HS)*invs + b1) -> X1 (fp32)
    pull_relu_kernel<<<((size_t)N * 16 + 255) / 256, 256, 0, stream>>>(
        rp, deg, col, HS, invs, b1, X1, N);

    // layer 2: HS = X1@W2 (bf16), then fused pull+relu+out-GEMM
    gemm_kernel<<<gemm_blocks, 256, 0, stream>>>(X1, W2, HS, N);
    pull_out_kernel<<<((size_t)N * 16 + 255) / 256, 256, 0, stream>>>(
        rp, deg, col, HS, invs, b2, Wout, bout, out, N);
}

// Round 4
// 494.106 us; speedup vs baseline: 11.9232x; 1.2491x over previous
//
#include <hip/hip_runtime.h>
#include <hip/hip_bf16.h>

#define HID 128
#define NCLASS 10
#define CHUNK 2048

typedef unsigned int uint;
typedef unsigned short ushort;
typedef __attribute__((ext_vector_type(8))) __bf16 bf16x8;
typedef __attribute__((ext_vector_type(4))) float f32x4;

// ---- bf16 helpers -----------------------------------------------------------
__device__ __forceinline__ uint bf16rne(float x) {
    uint u = __float_as_uint(x);
    return (u + 0x7FFFu + ((u >> 16) & 1u)) >> 16;
}
__device__ __forceinline__ uint pack2(float e0, float e1) {
    return bf16rne(e0) | (bf16rne(e1) << 16);
}
__device__ __forceinline__ void unpack2(uint w, float& lo, float& hi) {
    lo = __uint_as_float(w << 16);
    hi = __uint_as_float(w & 0xFFFF0000u);
}
// split fp32 pair into bf16-hi pair + bf16-lo (residual) pair
__device__ __forceinline__ void split2(float e0, float e1, uint& h, uint& l) {
    uint h0 = bf16rne(e0), h1 = bf16rne(e1);
    float r0 = e0 - __uint_as_float(h0 << 16);
    float r1 = e1 - __uint_as_float(h1 << 16);
    h = h0 | (h1 << 16);
    l = bf16rne(r0) | (bf16rne(r1) << 16);
}
__device__ __forceinline__ bf16x8 as_bf16x8(uint4 u) {
    return __builtin_bit_cast(bf16x8, u);
}

// ================================================================ W pre-pack
// Wp[hi|lo] in B-fragment order for mfma_f32_16x16x32_bf16:
// frag (s=kstep, t=ntile, lane): elems j=0..7 -> B[k = s*32 + (lane>>4)*8 + j][n = t*16 + (lane&15)]
// stored as uint4 at offset ((s*8+t)*64 + lane)*4 uints.
__global__ void pack_w_kernel(const float* __restrict__ W, uint* __restrict__ hi,
                              uint* __restrict__ lo) {
    const int s = blockIdx.x >> 3, t = blockIdx.x & 7, l = threadIdx.x;
    const int kb = s * 32 + (l >> 4) * 8, n = t * 16 + (l & 15);
    float f[8];
#pragma unroll
    for (int j = 0; j < 8; ++j) f[j] = W[(kb + j) * HID + n];
    uint4 h, lo4;
    split2(f[0], f[1], h.x, lo4.x);
    split2(f[2], f[3], h.y, lo4.y);
    split2(f[4], f[5], h.z, lo4.z);
    split2(f[6], f[7], h.w, lo4.w);
    const int fo = ((s * 8 + t) * 64 + l) * 4;
    *(uint4*)(hi + fo) = h;
    *(uint4*)(lo + fo) = lo4;
}

// ================================================================ MFMA GEMM
// H[Np x 128] = X[N x 128] @ W[128 x 128], bf16x2 split (fp32-equivalent).
// Block = 4 waves; wave handles 32 rows x 128 cols; K=128 in 4 steps of 32.
template <bool FP32IN>
__device__ __forceinline__ void gemm_body_mfma(
        const float* __restrict__ Xf,                                   // FP32IN
        const uint* __restrict__ Xhi, const uint* __restrict__ Xlo,     // !FP32IN
        const uint* __restrict__ Wphi, const uint* __restrict__ Wplo,
        ushort* __restrict__ HS, int N, int bidx, int tid) {
    const int wv = tid >> 6;
    const int l = tid & 63;
    const int cq = l >> 4;   // quad
    const int cm = l & 15;
    const long rowbase = (long)bidx * 128 + wv * 32;

    f32x4 acc[2][8];
#pragma unroll
    for (int rt = 0; rt < 2; ++rt)
#pragma unroll
        for (int t = 0; t < 8; ++t) acc[rt][t] = (f32x4)0.0f;

    for (int s = 0; s < 4; ++s) {
        bf16x8 ahi[2], alo[2];
#pragma unroll
        for (int rt = 0; rt < 2; ++rt) {
            const long row = rowbase + rt * 16 + cm;   // A-frag: m = lane&15
            if (FP32IN) {
                const long rc = row < N ? row : (N - 1);
                const float* xp = Xf + rc * HID + s * 32 + cq * 8;
                const float4 a0 = ((const float4*)xp)[0];
                const float4 a1 = ((const float4*)xp)[1];
                uint4 h, lo4;
                split2(a0.x, a0.y, h.x, lo4.x);
                split2(a0.z, a0.w, h.y, lo4.y);
                split2(a1.x, a1.y, h.z, lo4.z);
                split2(a1.z, a1.w, h.w, lo4.w);
                ahi[rt] = as_bf16x8(h);
                alo[rt] = as_bf16x8(lo4);
            } else {
                const long o = row * (HID / 2) + s * 16 + cq * 4;  // uint offsets
                ahi[rt] = as_bf16x8(*(const uint4*)(Xhi + o));
                alo[rt] = as_bf16x8(*(const uint4*)(Xlo + o));
            }
        }
#pragma unroll
        for (int t = 0; t < 8; ++t) {
            const int fo = ((s * 8 + t) * 64 + l) * 4;
            const bf16x8 bhi = as_bf16x8(*(const uint4*)(Wphi + fo));
            const bf16x8 blo = as_bf16x8(*(const uint4*)(Wplo + fo));
#pragma unroll
            for (int rt = 0; rt < 2; ++rt) {
                acc[rt][t] = __builtin_amdgcn_mfma_f32_16x16x32_bf16(ahi[rt], bhi, acc[rt][t], 0, 0, 0);
                acc[rt][t] = __builtin_amdgcn_mfma_f32_16x16x32_bf16(alo[rt], bhi, acc[rt][t], 0, 0, 0);
                acc[rt][t] = __builtin_amdgcn_mfma_f32_16x16x32_bf16(ahi[rt], blo, acc[rt][t], 0, 0, 0);
            }
        }
    }
    // epilogue: C/D layout col=lane&15, row=quad*4+reg -> bf16 stores
#pragma unroll
    for (int rt = 0; rt < 2; ++rt)
#pragma unroll
        for (int t = 0; t < 8; ++t)
#pragma unroll
            for (int r = 0; r < 4; ++r) {
                const long row = rowbase + rt * 16 + cq * 4 + r;
                HS[row * HID + t * 16 + cm] = (ushort)bf16rne(acc[rt][t][r]);
            }
}

// fat kernel: gemm1 (emb fp32 in) || degree count
__global__ __launch_bounds__(256) void gemm1_count_kernel(
        const float* __restrict__ emb, const uint* __restrict__ Wphi,
        const uint* __restrict__ Wplo, ushort* __restrict__ HS, int N,
        const int* __restrict__ dst, int* __restrict__ deg, int E, int GB) {
    if ((int)blockIdx.x < GB) {
        gemm_body_mfma<true>(emb, nullptr, nullptr, Wphi, Wplo, HS, N, blockIdx.x, threadIdx.x);
    } else {
        const int stride = (gridDim.x - GB) * 256;
        for (int e = ((int)blockIdx.x - GB) * 256 + threadIdx.x; e < E; e += stride)
            atomicAdd(&deg[dst[e]], 1);
    }
}

__global__ __launch_bounds__(256) void gemm2_kernel(
        const uint* __restrict__ Xhi, const uint* __restrict__ Xlo,
        const uint* __restrict__ Wphi, const uint* __restrict__ Wplo,
        ushort* __restrict__ HS, int N) {
    gemm_body_mfma<false>(nullptr, Xhi, Xlo, Wphi, Wplo, HS, N, blockIdx.x, threadIdx.x);
}

// ================================================================ scan + invs
__global__ __launch_bounds__(256) void scan1_kernel(const int* __restrict__ deg,
                                                    int* rp, int* bsum, float* invs, int N) {
    __shared__ int sh[256];
    const int t = threadIdx.x;
    const int idx0 = blockIdx.x * 1024 + t * 4;
    int v[4];
#pragma unroll
    for (int j = 0; j < 4; ++j) v[j] = (idx0 + j < N) ? deg[idx0 + j] : 0;
#pragma unroll
    for (int j = 0; j < 4; ++j)
        if (idx0 + j < N) invs[idx0 + j] = rsqrtf((float)v[j] + 1.0f);
    const int local = v[0] + v[1] + v[2] + v[3];
    sh[t] = local;
    __syncthreads();
    for (int off = 1; off < 256; off <<= 1) {
        int x = (t >= off) ? sh[t - off] : 0;
        __syncthreads();
        sh[t] += x;
        __syncthreads();
    }
    if (t == 255) bsum[blockIdx.x] = sh[255];
    int run = sh[t] - local;
#pragma unroll
    for (int j = 0; j < 4; ++j) {
        if (idx0 + j < N) rp[idx0 + j] = run;
        run += v[j];
    }
}

__global__ __launch_bounds__(128) void scan2_kernel(int* bsum, int nb) {
    __shared__ int sh[128];
    const int t = threadIdx.x;
    const int v = (t < nb) ? bsum[t] : 0;
    sh[t] = v;
    __syncthreads();
    for (int off = 1; off < 128; off <<= 1) {
        int x = (t >= off) ? sh[t - off] : 0;
        __syncthreads();
        sh[t] += x;
        __syncthreads();
    }
    if (t < nb) bsum[t] = sh[t] - v;
}

__global__ void scan3_kernel(int* rp, const int* __restrict__ bsum, int N) {
    int i = blockIdx.x * 256 + threadIdx.x;
    if (i < N) rp[i] += bsum[i >> 10];
}

// ================================================================ bucketed CSR fill
__global__ void bucket_init_kernel(const int* __restrict__ rp, int* gcursor, int* bounds, int NB) {
    int b = threadIdx.x;
    if (b < NB) {
        int v = rp[b << 10];
        gcursor[b] = v;
        bounds[b] = v;
    }
}

// Phase A: partition edges by dst bucket (dst>>10); staged entry = src | (dst&1023)<<17
__global__ __launch_bounds__(256) void partition_kernel(
        const int* __restrict__ src, const int* __restrict__ dst,
        int* __restrict__ gcursor, uint* __restrict__ staged, int E, int NB) {
    __shared__ int hist[128], lbase[128], loff[128];
    const int t = threadIdx.x;
    const int e0 = blockIdx.x * CHUNK;
    if (t < 128) { hist[t] = 0; loff[t] = 0; }
    __syncthreads();
    int b[8], sv[8], dl[8];
#pragma unroll
    for (int j = 0; j < 8; ++j) {
        const int e = e0 + t + j * 256;
        if (e < E) {
            const int d = dst[e];
            sv[j] = src[e];
            b[j] = d >> 10;
            dl[j] = d & 1023;
            atomicAdd(&hist[b[j]], 1);
        } else
            b[j] = -1;
    }
    __syncthreads();
    if (t < NB && hist[t] > 0) lbase[t] = atomicAdd(&gcursor[t], hist[t]);
    __syncthreads();
#pragma unroll
    for (int j = 0; j < 8; ++j) {
        if (b[j] >= 0) {
            const int pos = lbase[b[j]] + atomicAdd(&loff[b[j]], 1);
            staged[pos] = (uint)sv[j] | ((uint)dl[j] << 17);
        }
    }
}

// Phase B: per-bucket fill; rp/col windows are L2-resident. rp -> end offsets.
__global__ __launch_bounds__(256) void fill_bucket_kernel(
        const uint* __restrict__ staged, const int* __restrict__ bounds,
        int* __restrict__ rp, int* __restrict__ col, int E, int NB, int SUB) {
    const int b = blockIdx.x % NB;
    const int s = blockIdx.x / NB;
    const int w0 = bounds[b];
    const int w1 = (b + 1 < NB) ? bounds[b + 1] : E;
    const int base0 = b << 10;
    for (int base = w0 + s * CHUNK; base < w1; base += SUB * CHUNK) {
#pragma unroll
        for (int j = 0; j < 8; ++j) {
            const int i = base + threadIdx.x + j * 256;
            if (i < w1) {
                const uint u = staged[i];
                const int dn = base0 + (int)(u >> 17);
                const int p = atomicAdd(&rp[dn], 1);
                col[p] = (int)(u & 0x1FFFFu);
            }
        }
    }
}

// ================================================================ pull + relu -> bf16 hi/lo planes
// 16 lanes/node; lane holds 8 features (uint4 = 8 bf16).
__global__ __launch_bounds__(256) void pull_relu_kernel(
        const int* __restrict__ rp, const int* __restrict__ deg, const int* __restrict__ col,
        const uint* __restrict__ HS, const float* __restrict__ invs,
        const float* __restrict__ b, uint* __restrict__ Xhi, uint* __restrict__ Xlo, int N) {
    const int g = blockIdx.x * 256 + threadIdx.x;
    const int node = g >> 4;
    if (node >= N) return;
    const int lane = g & 15;
    const int d = deg[node];
    const int start = rp[node] - d;
    const uint4* H4 = (const uint4*)HS;

    float acc[8];
    {
        const float sn = invs[node];
        uint4 u = H4[(size_t)node * 16 + lane];
        float f[8];
        unpack2(u.x, f[0], f[1]); unpack2(u.y, f[2], f[3]);
        unpack2(u.z, f[4], f[5]); unpack2(u.w, f[6], f[7]);
#pragma unroll
        for (int j = 0; j < 8; ++j) acc[j] = f[j] * sn;
    }
    int i = 0;
    for (; i + 2 <= d; i += 2) {
        const int s0 = col[start + i];
        const int s1 = col[start + i + 1];
        const float ss0 = invs[s0];
        const float ss1 = invs[s1];
        const uint4 u0 = H4[(size_t)s0 * 16 + lane];
        const uint4 u1 = H4[(size_t)s1 * 16 + lane];
        float f0[8], f1[8];
        unpack2(u0.x, f0[0], f0[1]); unpack2(u0.y, f0[2], f0[3]);
        unpack2(u0.z, f0[4], f0[5]); unpack2(u0.w, f0[6], f0[7]);
        unpack2(u1.x, f1[0], f1[1]); unpack2(u1.y, f1[2], f1[3]);
        unpack2(u1.z, f1[4], f1[5]); unpack2(u1.w, f1[6], f1[7]);
#pragma unroll
        for (int j = 0; j < 8; ++j) acc[j] += f0[j] * ss0;
#pragma unroll
        for (int j = 0; j < 8; ++j) acc[j] += f1[j] * ss1;
    }
    if (i < d) {
        const int s0 = col[start + i];
        const float ss0 = invs[s0];
        const uint4 u0 = H4[(size_t)s0 * 16 + lane];
        float f0[8];
        unpack2(u0.x, f0[0], f0[1]); unpack2(u0.y, f0[2], f0[3]);
        unpack2(u0.z, f0[4], f0[5]); unpack2(u0.w, f0[6], f0[7]);
#pragma unroll
        for (int j = 0; j < 8; ++j) acc[j] += f0[j] * ss0;
    }
    const float sn = invs[node];
    float x[8];
#pragma unroll
    for (int j = 0; j < 8; ++j) x[j] = fmaxf(acc[j] * sn + b[lane * 8 + j], 0.0f);
    uint4 h, lo4;
    split2(x[0], x[1], h.x, lo4.x);
    split2(x[2], x[3], h.y, lo4.y);
    split2(x[4], x[5], h.z, lo4.z);
    split2(x[6], x[7], h.w, lo4.w);
    *(uint4*)&Xhi[(size_t)node * 64 + lane * 4] = h;
    *(uint4*)&Xlo[(size_t)node * 64 + lane * 4] = lo4;
}

// ================================================================ pull + relu + out-GEMM (128->10)
__global__ __launch_bounds__(256) void pull_out_kernel(
        const int* __restrict__ rp, const int* __restrict__ deg, const int* __restrict__ col,
        const uint* __restrict__ HS, const float* __restrict__ invs,
        const float* __restrict__ b2, const float* __restrict__ Wout,
        const float* __restrict__ bout, float* __restrict__ OUT, int N) {
    __shared__ float Wl[HID * 11];
    for (int i = threadIdx.x; i < HID * NCLASS; i += 256)
        Wl[(i / NCLASS) * 11 + (i % NCLASS)] = Wout[i];
    __syncthreads();

    const int g = blockIdx.x * 256 + threadIdx.x;
    const int node = g >> 4;
    if (node >= N) return;
    const int lane = g & 15;
    const int d = deg[node];
    const int start = rp[node] - d;
    const uint4* H4 = (const uint4*)HS;

    float acc[8];
    {
        const float sn = invs[node];
        uint4 u = H4[(size_t)node * 16 + lane];
        float f[8];
        unpack2(u.x, f[0], f[1]); unpack2(u.y, f[2], f[3]);
        unpack2(u.z, f[4], f[5]); unpack2(u.w, f[6], f[7]);
#pragma unroll
        for (int j = 0; j < 8; ++j) acc[j] = f[j] * sn;
    }
    int i = 0;
    for (; i + 2 <= d; i += 2) {
        const int s0 = col[start + i];
        const int s1 = col[start + i + 1];
        const float ss0 = invs[s0];
        const float ss1 = invs[s1];
        const uint4 u0 = H4[(size_t)s0 * 16 + lane];
        const uint4 u1 = H4[(size_t)s1 * 16 + lane];
        float f0[8], f1[8];
        unpack2(u0.x, f0[0], f0[1]); unpack2(u0.y, f0[2], f0[3]);
        unpack2(u0.z, f0[4], f0[5]); unpack2(u0.w, f0[6], f0[7]);
        unpack2(u1.x, f1[0], f1[1]); unpack2(u1.y, f1[2], f1[3]);
        unpack2(u1.z, f1[4], f1[5]); unpack2(u1.w, f1[6], f1[7]);
#pragma unroll
        for (int j = 0; j < 8; ++j) acc[j] += f0[j] * ss0;
#pragma unroll
        for (int j = 0; j < 8; ++j) acc[j] += f1[j] * ss1;
    }
    if (i < d) {
        const int s0 = col[start + i];
        const float ss0 = invs[s0];
        const uint4 u0 = H4[(size_t)s0 * 16 + lane];
        float f0[8];
        unpack2(u0.x, f0[0], f0[1]); unpack2(u0.y, f0[2], f0[3]);
        unpack2(u0.z, f0[4], f0[5]); unpack2(u0.w, f0[6], f0[7]);
#pragma unroll
        for (int j = 0; j < 8; ++j) acc[j] += f0[j] * ss0;
    }
    const float sn = invs[node];
    float x[8];
#pragma unroll
    for (int j = 0; j < 8; ++j) x[j] = fmaxf(acc[j] * sn + b2[lane * 8 + j], 0.0f);

    float p[NCLASS];
#pragma unroll
    for (int c = 0; c < NCLASS; ++c) {
        float s = 0.0f;
#pragma unroll
        for (int j = 0; j < 8; ++j) s += x[j] * Wl[(lane * 8 + j) * 11 + c];
        p[c] = s;
    }
#pragma unroll
    for (int c = 0; c < NCLASS; ++c) {
#pragma unroll
        for (int off = 8; off > 0; off >>= 1) p[c] += __shfl_xor(p[c], off, 16);
    }
    if (lane < NCLASS) OUT[(size_t)node * NCLASS + lane] = p[lane] + bout[lane];
}

// ================================================================ launch
extern "C" void kernel_launch(void* const* d_in, const int* in_sizes, int n_in,
                              void* d_out, int out_size, void* d_ws, size_t ws_size,
                              hipStream_t stream) {
    const int* ei     = (const int*)d_in[0];
    const float* emb  = (const float*)d_in[1];
    const float* W1   = (const float*)d_in[2];
    const float* b1   = (const float*)d_in[3];
    const float* W2   = (const float*)d_in[4];
    const float* b2   = (const float*)d_in[5];
    const float* Wout = (const float*)d_in[6];
    const float* bout = (const float*)d_in[7];
    float* out        = (float*)d_out;

    const int E = in_sizes[0] / 2;
    const int N = in_sizes[1] / HID;
    const int* src = ei;
    const int* dst = ei + E;
    (void)ws_size; (void)n_in; (void)out_size;

    const int GB = (N + 127) / 128;       // gemm blocks (782)
    const long Np = (long)GB * 128;       // padded rows
    const int NB = (N + 1023) >> 10;      // buckets (98)
    const int nb = (N + 1023) / 1024;     // scan phase-1 blocks

    char* ws = (char*)d_ws;
    size_t off = 0;
    auto alloc = [&](size_t bytes) {
        void* p = ws + off;
        off = (off + bytes + 4095) & ~(size_t)4095;
        return p;
    };
    int*   deg     = (int*)alloc((size_t)N * 4);
    int*   rp      = (int*)alloc((size_t)N * 4);
    float* invs    = (float*)alloc((size_t)N * 4);
    int*   bsum    = (int*)alloc(128 * 4);
    int*   bounds  = (int*)alloc(128 * 4);
    int*   gcursor = (int*)alloc(128 * 4);
    int*   col     = (int*)alloc((size_t)E * 4);
    uint*  staged  = (uint*)alloc((size_t)E * 4);
    uint*  Wp1hi   = (uint*)alloc(HID * HID * 2);
    uint*  Wp1lo   = (uint*)alloc(HID * HID * 2);
    uint*  Wp2hi   = (uint*)alloc(HID * HID * 2);
    uint*  Wp2lo   = (uint*)alloc(HID * HID * 2);
    uint*  HS      = (uint*)alloc((size_t)Np * HID * 2);  // bf16 features
    uint*  X1hi    = (uint*)alloc((size_t)Np * HID * 2);  // bf16 hidden hi
    uint*  X1lo    = (uint*)alloc((size_t)Np * HID * 2);  // bf16 hidden lo

    // pack weights into B-fragment order (hi/lo planes)
    pack_w_kernel<<<32, 64, 0, stream>>>(W1, Wp1hi, Wp1lo);
    pack_w_kernel<<<32, 64, 0, stream>>>(W2, Wp2hi, Wp2lo);

    // gemm1 (emb@W1 -> HS bf16) || degree count
    hipMemsetAsync(deg, 0, (size_t)N * 4, stream);
    gemm1_count_kernel<<<GB + 480, 256, 0, stream>>>(emb, Wp1hi, Wp1lo, (ushort*)HS, N,
                                                     dst, deg, E, GB);

    // CSR row pointers + invs
    scan1_kernel<<<nb, 256, 0, stream>>>(deg, rp, bsum, invs, N);
    scan2_kernel<<<1, 128, 0, stream>>>(bsum, nb);
    scan3_kernel<<<(N + 255) / 256, 256, 0, stream>>>(rp, bsum, N);

    // bucketed fill
    bucket_init_kernel<<<1, 128, 0, stream>>>(rp, gcursor, bounds, NB);
    partition_kernel<<<(E + CHUNK - 1) / CHUNK, 256, 0, stream>>>(src, dst, gcursor, staged, E, NB);
    const int SUB = 9;
    fill_bucket_kernel<<<NB * SUB, 256, 0, stream>>>(staged, bounds, rp, col, E, NB, SUB);

    // layer 1 aggregate: x1 = relu(pull(HS)*invs + b1) -> bf16 hi/lo planes
    pull_relu_kernel<<<((size_t)N * 16 + 255) / 256, 256, 0, stream>>>(
        rp, deg, col, HS, invs, b1, X1hi, X1lo, N);

    // layer 2: HS = X1@W2 (bf16), then fused pull+relu+out-GEMM
    gemm2_kernel<<<GB, 256, 0, stream>>>(X1hi, X1lo, Wp2hi, Wp2lo, (ushort*)HS, N);
    pull_out_kernel<<<((size_t)N * 16 + 255) / 256, 256, 0, stream>>>(
        rp, deg, col, HS, invs, b2, Wout, bout, out, N);
}

// Round 5
// 449.043 us; speedup vs baseline: 13.1198x; 1.1004x over previous
//
#include <hip/hip_runtime.h>
#include <hip/hip_bf16.h>

#define HID 128
#define NCLASS 10
#define PCHUNK 8192

typedef unsigned int uint;
typedef unsigned short ushort;
typedef __attribute__((ext_vector_type(8))) __bf16 bf16x8;
typedef __attribute__((ext_vector_type(4))) float f32x4;

// ---- bf16 helpers -----------------------------------------------------------
__device__ __forceinline__ uint bf16rne(float x) {
    uint u = __float_as_uint(x);
    return (u + 0x7FFFu + ((u >> 16) & 1u)) >> 16;
}
__device__ __forceinline__ uint pack2(float e0, float e1) {
    return bf16rne(e0) | (bf16rne(e1) << 16);
}
__device__ __forceinline__ void unpack2(uint w, float& lo, float& hi) {
    lo = __uint_as_float(w << 16);
    hi = __uint_as_float(w & 0xFFFF0000u);
}
__device__ __forceinline__ void split2(float e0, float e1, uint& h, uint& l) {
    uint h0 = bf16rne(e0), h1 = bf16rne(e1);
    float r0 = e0 - __uint_as_float(h0 << 16);
    float r1 = e1 - __uint_as_float(h1 << 16);
    h = h0 | (h1 << 16);
    l = bf16rne(r0) | (bf16rne(r1) << 16);
}
__device__ __forceinline__ bf16x8 as_bf16x8(uint4 u) {
    return __builtin_bit_cast(bf16x8, u);
}

// ================================================================ W pre-pack
// Fragment order (symmetric for A and B roles of mfma_f32_16x16x32_bf16):
// slot (s,t,lane): elems j=0..7 -> W[k = s*32 + (lane>>4)*8 + j][c = t*16 + (lane&15)]
__global__ void pack_w_kernel(const float* __restrict__ W, uint* __restrict__ hi,
                              uint* __restrict__ lo) {
    const int s = blockIdx.x >> 3, t = blockIdx.x & 7, l = threadIdx.x;
    const int kb = s * 32 + (l >> 4) * 8, n = t * 16 + (l & 15);
    float f[8];
#pragma unroll
    for (int j = 0; j < 8; ++j) f[j] = W[(kb + j) * HID + n];
    uint4 h, lo4;
    split2(f[0], f[1], h.x, lo4.x);
    split2(f[2], f[3], h.y, lo4.y);
    split2(f[4], f[5], h.z, lo4.z);
    split2(f[6], f[7], h.w, lo4.w);
    const int fo = ((s * 8 + t) * 64 + l) * 4;
    *(uint4*)(hi + fo) = h;
    *(uint4*)(lo + fo) = lo4;
}

// ================================================================ MFMA GEMM  (A = W, B = X)
// D[m=wcol][n=xrow]: wave does 32 xrows (2 n-tiles) x 128 wcols (8 m-tiles).
// Block = 4 waves = 128 rows. bf16x2 split: Whi*Xhi + Whi*Xlo + Wlo*Xhi.
template <bool FP32IN>
__device__ __forceinline__ void gemm_body_mfma(
        const float* __restrict__ Xf,
        const uint* __restrict__ Xhi, const uint* __restrict__ Xlo,
        const uint* __restrict__ Wphi, const uint* __restrict__ Wplo,
        ushort* __restrict__ HS, int N, int bidx, int tid) {
    const int wv = tid >> 6;
    const int l = tid & 63;
    const int q = l >> 4;
    const int cm = l & 15;
    const long rowbase = (long)bidx * 128 + wv * 32;

    // hoist ALL B-frags (X rows, hi/lo) for K=128 before the MFMA stream
    bf16x8 bhi[2][4], blo[2][4];
#pragma unroll
    for (int rt = 0; rt < 2; ++rt) {
        const long row = rowbase + rt * 16 + cm;
        const long rc = row < N ? row : (N - 1);
#pragma unroll
        for (int s = 0; s < 4; ++s) {
            if (FP32IN) {
                const float* xp = Xf + rc * HID + s * 32 + q * 8;
                const float4 a0 = ((const float4*)xp)[0];
                const float4 a1 = ((const float4*)xp)[1];
                uint4 h, lo4;
                split2(a0.x, a0.y, h.x, lo4.x);
                split2(a0.z, a0.w, h.y, lo4.y);
                split2(a1.x, a1.y, h.z, lo4.z);
                split2(a1.z, a1.w, h.w, lo4.w);
                bhi[rt][s] = as_bf16x8(h);
                blo[rt][s] = as_bf16x8(lo4);
            } else {
                const long o = rc * (HID / 2) + s * 16 + q * 4;  // uint offsets
                bhi[rt][s] = as_bf16x8(*(const uint4*)(Xhi + o));
                blo[rt][s] = as_bf16x8(*(const uint4*)(Xlo + o));
            }
        }
    }

    f32x4 acc[2][8];
#pragma unroll
    for (int rt = 0; rt < 2; ++rt)
#pragma unroll
        for (int t = 0; t < 8; ++t) acc[rt][t] = (f32x4)0.0f;

#pragma unroll
    for (int s = 0; s < 4; ++s) {
#pragma unroll
        for (int t = 0; t < 8; ++t) {
            const int fo = ((s * 8 + t) * 64 + l) * 4;
            const bf16x8 whi = as_bf16x8(*(const uint4*)(Wphi + fo));
            const bf16x8 wlo = as_bf16x8(*(const uint4*)(Wplo + fo));
#pragma unroll
            for (int rt = 0; rt < 2; ++rt) {
                acc[rt][t] = __builtin_amdgcn_mfma_f32_16x16x32_bf16(whi, bhi[rt][s], acc[rt][t], 0, 0, 0);
                acc[rt][t] = __builtin_amdgcn_mfma_f32_16x16x32_bf16(whi, blo[rt][s], acc[rt][t], 0, 0, 0);
                acc[rt][t] = __builtin_amdgcn_mfma_f32_16x16x32_bf16(wlo, bhi[rt][s], acc[rt][t], 0, 0, 0);
            }
        }
    }

    // epilogue: lane holds row (rowbase+rt*16+cm), cols t*16 + q*4 + r -> 8B stores
#pragma unroll
    for (int rt = 0; rt < 2; ++rt) {
        const long row = rowbase + rt * 16 + cm;
        if (row < N) {
#pragma unroll
            for (int t = 0; t < 8; ++t) {
                uint2 o;
                o.x = pack2(acc[rt][t][0], acc[rt][t][1]);
                o.y = pack2(acc[rt][t][2], acc[rt][t][3]);
                *(uint2*)&HS[row * HID + t * 16 + q * 4] = o;
            }
        }
    }
}

// fat kernel: gemm1 (emb fp32 in) || degree count
__global__ __launch_bounds__(256) void gemm1_count_kernel(
        const float* __restrict__ emb, const uint* __restrict__ Wphi,
        const uint* __restrict__ Wplo, ushort* __restrict__ HS, int N,
        const int* __restrict__ dst, int* __restrict__ deg, int E, int GB) {
    if ((int)blockIdx.x < GB) {
        gemm_body_mfma<true>(emb, nullptr, nullptr, Wphi, Wplo, HS, N, blockIdx.x, threadIdx.x);
    } else {
        const int stride = (gridDim.x - GB) * 256;
        for (int e = ((int)blockIdx.x - GB) * 256 + threadIdx.x; e < E; e += stride)
            atomicAdd(&deg[dst[e]], 1);
    }
}

__global__ __launch_bounds__(256) void gemm2_kernel(
        const uint* __restrict__ Xhi, const uint* __restrict__ Xlo,
        const uint* __restrict__ Wphi, const uint* __restrict__ Wplo,
        ushort* __restrict__ HS, int N) {
    gemm_body_mfma<false>(nullptr, Xhi, Xlo, Wphi, Wplo, HS, N, blockIdx.x, threadIdx.x);
}

// ================================================================ scan + invs
__global__ __launch_bounds__(256) void scan1_kernel(const int* __restrict__ deg,
                                                    int* rp, int* bsum, float* invs, int N) {
    __shared__ int sh[256];
    const int t = threadIdx.x;
    const int idx0 = blockIdx.x * 1024 + t * 4;
    int v[4];
#pragma unroll
    for (int j = 0; j < 4; ++j) v[j] = (idx0 + j < N) ? deg[idx0 + j] : 0;
#pragma unroll
    for (int j = 0; j < 4; ++j)
        if (idx0 + j < N) invs[idx0 + j] = rsqrtf((float)v[j] + 1.0f);
    const int local = v[0] + v[1] + v[2] + v[3];
    sh[t] = local;
    __syncthreads();
    for (int off = 1; off < 256; off <<= 1) {
        int x = (t >= off) ? sh[t - off] : 0;
        __syncthreads();
        sh[t] += x;
        __syncthreads();
    }
    if (t == 255) bsum[blockIdx.x] = sh[255];
    int run = sh[t] - local;
#pragma unroll
    for (int j = 0; j < 4; ++j) {
        if (idx0 + j < N) rp[idx0 + j] = run;
        run += v[j];
    }
}

__global__ __launch_bounds__(128) void scan2_kernel(int* bsum, int nb) {
    __shared__ int sh[128];
    const int t = threadIdx.x;
    const int v = (t < nb) ? bsum[t] : 0;
    sh[t] = v;
    __syncthreads();
    for (int off = 1; off < 128; off <<= 1) {
        int x = (t >= off) ? sh[t - off] : 0;
        __syncthreads();
        sh[t] += x;
        __syncthreads();
    }
    if (t < nb) bsum[t] = sh[t] - v;
}

__global__ void scan3_kernel(int* rp, const int* __restrict__ bsum, int N) {
    int i = blockIdx.x * 256 + threadIdx.x;
    if (i < N) rp[i] += bsum[i >> 10];
}

// ================================================================ bucketed CSR fill
// 256-node buckets; ONE block per bucket in phase B => single-XCD write locality.
__global__ void bucket_init_kernel(const int* __restrict__ rp, int* gcursor, int* bounds, int NB) {
    int b = threadIdx.x;
    if (b < NB) {
        int v = rp[b << 8];
        gcursor[b] = v;
        bounds[b] = v;
    }
}

// Phase A: two-pass partition by bucket (dst>>8). staged = src | (dst&255)<<17
__global__ __launch_bounds__(256) void partition_kernel(
        const int* __restrict__ src, const int* __restrict__ dst,
        int* __restrict__ gcursor, uint* __restrict__ staged, int E, int NB) {
    __shared__ int hist[400], lbase[400], loff[400];
    const int t = threadIdx.x;
    const int e0 = blockIdx.x * PCHUNK;
    for (int i = t; i < NB; i += 256) { hist[i] = 0; loff[i] = 0; }
    __syncthreads();
#pragma unroll
    for (int j = 0; j < PCHUNK / 256; ++j) {
        const int e = e0 + j * 256 + t;
        if (e < E) atomicAdd(&hist[dst[e] >> 8], 1);
    }
    __syncthreads();
    for (int b = t; b < NB; b += 256)
        if (hist[b] > 0) lbase[b] = atomicAdd(&gcursor[b], hist[b]);
    __syncthreads();
#pragma unroll
    for (int j = 0; j < PCHUNK / 256; ++j) {
        const int e = e0 + j * 256 + t;
        if (e < E) {
            const int d = dst[e];
            const int b = d >> 8;
            const int pos = lbase[b] + atomicAdd(&loff[b], 1);
            staged[pos] = (uint)src[e] | ((uint)(d & 255) << 17);
        }
    }
}

// Phase B: one block per bucket; rp(1KB)/col(~16KB) windows stay in ONE XCD's L2.
__global__ __launch_bounds__(256) void fill_bucket_kernel(
        const uint* __restrict__ staged, const int* __restrict__ bounds,
        int* __restrict__ rp, int* __restrict__ col, int E, int NB) {
    const int b = blockIdx.x;
    const int w0 = bounds[b];
    const int w1 = (b + 1 < NB) ? bounds[b + 1] : E;
    const int base0 = b << 8;
    for (int i = w0 + (int)threadIdx.x; i < w1; i += 256) {
        const uint u = staged[i];
        const int p = atomicAdd(&rp[base0 + (int)(u >> 17)], 1);
        col[p] = (int)(u & 0x1FFFFu);
    }
}

// ================================================================ pull + relu -> bf16 hi/lo planes
__global__ __launch_bounds__(256) void pull_relu_kernel(
        const int* __restrict__ rp, const int* __restrict__ deg, const int* __restrict__ col,
        const uint* __restrict__ HS, const float* __restrict__ invs,
        const float* __restrict__ b, uint* __restrict__ Xhi, uint* __restrict__ Xlo, int N) {
    const int g = blockIdx.x * 256 + threadIdx.x;
    const int node = g >> 4;
    if (node >= N) return;
    const int lane = g & 15;
    const int d = deg[node];
    const int start = rp[node] - d;
    const uint4* H4 = (const uint4*)HS;

    float acc[8];
    {
        const float sn = invs[node];
        uint4 u = H4[(size_t)node * 16 + lane];
        float f[8];
        unpack2(u.x, f[0], f[1]); unpack2(u.y, f[2], f[3]);
        unpack2(u.z, f[4], f[5]); unpack2(u.w, f[6], f[7]);
#pragma unroll
        for (int j = 0; j < 8; ++j) acc[j] = f[j] * sn;
    }
    int i = 0;
    for (; i + 2 <= d; i += 2) {
        const int s0 = col[start + i];
        const int s1 = col[start + i + 1];
        const float ss0 = invs[s0];
        const float ss1 = invs[s1];
        const uint4 u0 = H4[(size_t)s0 * 16 + lane];
        const uint4 u1 = H4[(size_t)s1 * 16 + lane];
        float f0[8], f1[8];
        unpack2(u0.x, f0[0], f0[1]); unpack2(u0.y, f0[2], f0[3]);
        unpack2(u0.z, f0[4], f0[5]); unpack2(u0.w, f0[6], f0[7]);
        unpack2(u1.x, f1[0], f1[1]); unpack2(u1.y, f1[2], f1[3]);
        unpack2(u1.z, f1[4], f1[5]); unpack2(u1.w, f1[6], f1[7]);
#pragma unroll
        for (int j = 0; j < 8; ++j) acc[j] += f0[j] * ss0;
#pragma unroll
        for (int j = 0; j < 8; ++j) acc[j] += f1[j] * ss1;
    }
    if (i < d) {
        const int s0 = col[start + i];
        const float ss0 = invs[s0];
        const uint4 u0 = H4[(size_t)s0 * 16 + lane];
        float f0[8];
        unpack2(u0.x, f0[0], f0[1]); unpack2(u0.y, f0[2], f0[3]);
        unpack2(u0.z, f0[4], f0[5]); unpack2(u0.w, f0[6], f0[7]);
#pragma unroll
        for (int j = 0; j < 8; ++j) acc[j] += f0[j] * ss0;
    }
    const float sn = invs[node];
    float x[8];
#pragma unroll
    for (int j = 0; j < 8; ++j) x[j] = fmaxf(acc[j] * sn + b[lane * 8 + j], 0.0f);
    uint4 h, lo4;
    split2(x[0], x[1], h.x, lo4.x);
    split2(x[2], x[3], h.y, lo4.y);
    split2(x[4], x[5], h.z, lo4.z);
    split2(x[6], x[7], h.w, lo4.w);
    *(uint4*)&Xhi[(size_t)node * 64 + lane * 4] = h;
    *(uint4*)&Xlo[(size_t)node * 64 + lane * 4] = lo4;
}

// ================================================================ pull + relu + out-GEMM (128->10)
__global__ __launch_bounds__(256) void pull_out_kernel(
        const int* __restrict__ rp, const int* __restrict__ deg, const int* __restrict__ col,
        const uint* __restrict__ HS, const float* __restrict__ invs,
        const float* __restrict__ b2, const float* __restrict__ Wout,
        const float* __restrict__ bout, float* __restrict__ OUT, int N) {
    __shared__ float Wl[HID * 11];
    for (int i = threadIdx.x; i < HID * NCLASS; i += 256)
        Wl[(i / NCLASS) * 11 + (i % NCLASS)] = Wout[i];
    __syncthreads();

    const int g = blockIdx.x * 256 + threadIdx.x;
    const int node = g >> 4;
    if (node >= N) return;
    const int lane = g & 15;
    const int d = deg[node];
    const int start = rp[node] - d;
    const uint4* H4 = (const uint4*)HS;

    float acc[8];
    {
        const float sn = invs[node];
        uint4 u = H4[(size_t)node * 16 + lane];
        float f[8];
        unpack2(u.x, f[0], f[1]); unpack2(u.y, f[2], f[3]);
        unpack2(u.z, f[4], f[5]); unpack2(u.w, f[6], f[7]);
#pragma unroll
        for (int j = 0; j < 8; ++j) acc[j] = f[j] * sn;
    }
    int i = 0;
    for (; i + 2 <= d; i += 2) {
        const int s0 = col[start + i];
        const int s1 = col[start + i + 1];
        const float ss0 = invs[s0];
        const float ss1 = invs[s1];
        const uint4 u0 = H4[(size_t)s0 * 16 + lane];
        const uint4 u1 = H4[(size_t)s1 * 16 + lane];
        float f0[8], f1[8];
        unpack2(u0.x, f0[0], f0[1]); unpack2(u0.y, f0[2], f0[3]);
        unpack2(u0.z, f0[4], f0[5]); unpack2(u0.w, f0[6], f0[7]);
        unpack2(u1.x, f1[0], f1[1]); unpack2(u1.y, f1[2], f1[3]);
        unpack2(u1.z, f1[4], f1[5]); unpack2(u1.w, f1[6], f1[7]);
#pragma unroll
        for (int j = 0; j < 8; ++j) acc[j] += f0[j] * ss0;
#pragma unroll
        for (int j = 0; j < 8; ++j) acc[j] += f1[j] * ss1;
    }
    if (i < d) {
        const int s0 = col[start + i];
        const float ss0 = invs[s0];
        const uint4 u0 = H4[(size_t)s0 * 16 + lane];
        float f0[8];
        unpack2(u0.x, f0[0], f0[1]); unpack2(u0.y, f0[2], f0[3]);
        unpack2(u0.z, f0[4], f0[5]); unpack2(u0.w, f0[6], f0[7]);
#pragma unroll
        for (int j = 0; j < 8; ++j) acc[j] += f0[j] * ss0;
    }
    const float sn = invs[node];
    float x[8];
#pragma unroll
    for (int j = 0; j < 8; ++j) x[j] = fmaxf(acc[j] * sn + b2[lane * 8 + j], 0.0f);

    float p[NCLASS];
#pragma unroll
    for (int c = 0; c < NCLASS; ++c) {
        float s = 0.0f;
#pragma unroll
        for (int j = 0; j < 8; ++j) s += x[j] * Wl[(lane * 8 + j) * 11 + c];
        p[c] = s;
    }
#pragma unroll
    for (int c = 0; c < NCLASS; ++c) {
#pragma unroll
        for (int off = 8; off > 0; off >>= 1) p[c] += __shfl_xor(p[c], off, 16);
    }
    if (lane < NCLASS) OUT[(size_t)node * NCLASS + lane] = p[lane] + bout[lane];
}

// ================================================================ launch
extern "C" void kernel_launch(void* const* d_in, const int* in_sizes, int n_in,
                              void* d_out, int out_size, void* d_ws, size_t ws_size,
                              hipStream_t stream) {
    const int* ei     = (const int*)d_in[0];
    const float* emb  = (const float*)d_in[1];
    const float* W1   = (const float*)d_in[2];
    const float* b1   = (const float*)d_in[3];
    const float* W2   = (const float*)d_in[4];
    const float* b2   = (const float*)d_in[5];
    const float* Wout = (const float*)d_in[6];
    const float* bout = (const float*)d_in[7];
    float* out        = (float*)d_out;

    const int E = in_sizes[0] / 2;
    const int N = in_sizes[1] / HID;
    const int* src = ei;
    const int* dst = ei + E;
    (void)ws_size; (void)n_in; (void)out_size;

    const int GB = (N + 127) / 128;      // gemm blocks (782)
    const int NB = (N + 255) >> 8;       // 256-node buckets (391)
    const int nb = (N + 1023) / 1024;    // scan phase-1 blocks (98)

    char* ws = (char*)d_ws;
    size_t off = 0;
    auto alloc = [&](size_t bytes) {
        void* p = ws + off;
        off = (off + bytes + 4095) & ~(size_t)4095;
        return p;
    };
    int*   deg     = (int*)alloc((size_t)N * 4);
    int*   rp      = (int*)alloc((size_t)N * 4);
    float* invs    = (float*)alloc((size_t)N * 4);
    int*   bsum    = (int*)alloc(128 * 4);
    int*   bounds  = (int*)alloc(512 * 4);
    int*   gcursor = (int*)alloc(512 * 4);
    int*   col     = (int*)alloc((size_t)E * 4);
    uint*  staged  = (uint*)alloc((size_t)E * 4);
    uint*  Wp1hi   = (uint*)alloc(HID * HID * 2);
    uint*  Wp1lo   = (uint*)alloc(HID * HID * 2);
    uint*  Wp2hi   = (uint*)alloc(HID * HID * 2);
    uint*  Wp2lo   = (uint*)alloc(HID * HID * 2);
    uint*  HS      = (uint*)alloc((size_t)N * HID * 2);  // bf16 features
    uint*  X1hi    = (uint*)alloc((size_t)N * HID * 2);  // bf16 hidden hi
    uint*  X1lo    = (uint*)alloc((size_t)N * HID * 2);  // bf16 hidden lo

    // pack weights (shared fragment layout for A/B roles)
    pack_w_kernel<<<32, 64, 0, stream>>>(W1, Wp1hi, Wp1lo);
    pack_w_kernel<<<32, 64, 0, stream>>>(W2, Wp2hi, Wp2lo);

    // gemm1 (emb@W1 -> HS bf16) || degree count
    hipMemsetAsync(deg, 0, (size_t)N * 4, stream);
    gemm1_count_kernel<<<GB + 480, 256, 0, stream>>>(emb, Wp1hi, Wp1lo, (ushort*)HS, N,
                                                     dst, deg, E, GB);

    // CSR row pointers + invs
    scan1_kernel<<<nb, 256, 0, stream>>>(deg, rp, bsum, invs, N);
    scan2_kernel<<<1, 128, 0, stream>>>(bsum, nb);
    scan3_kernel<<<(N + 255) / 256, 256, 0, stream>>>(rp, bsum, N);

    // bucketed fill (single-writer buckets)
    bucket_init_kernel<<<1, 512, 0, stream>>>(rp, gcursor, bounds, NB);
    partition_kernel<<<(E + PCHUNK - 1) / PCHUNK, 256, 0, stream>>>(src, dst, gcursor, staged, E, NB);
    fill_bucket_kernel<<<NB, 256, 0, stream>>>(staged, bounds, rp, col, E, NB);

    // layer 1 aggregate: x1 = relu(pull(HS)*invs + b1) -> bf16 hi/lo planes
    pull_relu_kernel<<<((size_t)N * 16 + 255) / 256, 256, 0, stream>>>(
        rp, deg, col, HS, invs, b1, X1hi, X1lo, N);

    // layer 2: HS = X1@W2 (bf16), then fused pull+relu+out-GEMM
    gemm2_kernel<<<GB, 256, 0, stream>>>(X1hi, X1lo, Wp2hi, Wp2lo, (ushort*)HS, N);
    pull_out_kernel<<<((size_t)N * 16 + 255) / 256, 256, 0, stream>>>(
        rp, deg, col, HS, invs, b2, Wout, bout, out, N);
}

// Round 6
// 357.913 us; speedup vs baseline: 16.4603x; 1.2546x over previous
//
#include <hip/hip_runtime.h>
#include <hip/hip_bf16.h>

#define HID 128
#define NCLASS 10
#define PCHUNK 8192
#define HB 256  // hist partner blocks

typedef unsigned int uint;
typedef unsigned short ushort;
typedef __attribute__((ext_vector_type(8))) __bf16 bf16x8;
typedef __attribute__((ext_vector_type(4))) float f32x4;

// ---- bf16 helpers -----------------------------------------------------------
__device__ __forceinline__ uint bf16rne(float x) {
    uint u = __float_as_uint(x);
    return (u + 0x7FFFu + ((u >> 16) & 1u)) >> 16;
}
__device__ __forceinline__ uint pack2(float e0, float e1) {
    return bf16rne(e0) | (bf16rne(e1) << 16);
}
__device__ __forceinline__ void unpack2(uint w, float& lo, float& hi) {
    lo = __uint_as_float(w << 16);
    hi = __uint_as_float(w & 0xFFFF0000u);
}
__device__ __forceinline__ void split2(float e0, float e1, uint& h, uint& l) {
    uint h0 = bf16rne(e0), h1 = bf16rne(e1);
    float r0 = e0 - __uint_as_float(h0 << 16);
    float r1 = e1 - __uint_as_float(h1 << 16);
    h = h0 | (h1 << 16);
    l = bf16rne(r0) | (bf16rne(r1) << 16);
}
__device__ __forceinline__ bf16x8 as_bf16x8(uint4 u) {
    return __builtin_bit_cast(bf16x8, u);
}
__device__ __forceinline__ void unpack8(uint4 u, float* f) {
    unpack2(u.x, f[0], f[1]); unpack2(u.y, f[2], f[3]);
    unpack2(u.z, f[4], f[5]); unpack2(u.w, f[6], f[7]);
}

// ================================================================ W pre-pack (fragment order)
__global__ void pack_w_kernel(const float* __restrict__ W, uint* __restrict__ hi,
                              uint* __restrict__ lo) {
    const int s = blockIdx.x >> 3, t = blockIdx.x & 7, l = threadIdx.x;
    const int kb = s * 32 + (l >> 4) * 8, n = t * 16 + (l & 15);
    float f[8];
#pragma unroll
    for (int j = 0; j < 8; ++j) f[j] = W[(kb + j) * HID + n];
    uint4 h, lo4;
    split2(f[0], f[1], h.x, lo4.x);
    split2(f[2], f[3], h.y, lo4.y);
    split2(f[4], f[5], h.z, lo4.z);
    split2(f[6], f[7], h.w, lo4.w);
    const int fo = ((s * 8 + t) * 64 + l) * 4;
    *(uint4*)(hi + fo) = h;
    *(uint4*)(lo + fo) = lo4;
}

// ================================================================ MFMA GEMM (A=W, B=X)
template <bool FP32IN>
__device__ __forceinline__ void gemm_body_mfma(
        const float* __restrict__ Xf,
        const uint* __restrict__ Xhi, const uint* __restrict__ Xlo,
        const uint* __restrict__ Wphi, const uint* __restrict__ Wplo,
        ushort* __restrict__ HS, int N, int bidx, int tid) {
    const int wv = tid >> 6;
    const int l = tid & 63;
    const int q = l >> 4;
    const int cm = l & 15;
    const long rowbase = (long)bidx * 128 + wv * 32;

    bf16x8 bhi[2][4], blo[2][4];
#pragma unroll
    for (int rt = 0; rt < 2; ++rt) {
        const long row = rowbase + rt * 16 + cm;
        const long rc = row < N ? row : (N - 1);
#pragma unroll
        for (int s = 0; s < 4; ++s) {
            if (FP32IN) {
                const float* xp = Xf + rc * HID + s * 32 + q * 8;
                const float4 a0 = ((const float4*)xp)[0];
                const float4 a1 = ((const float4*)xp)[1];
                uint4 h, lo4;
                split2(a0.x, a0.y, h.x, lo4.x);
                split2(a0.z, a0.w, h.y, lo4.y);
                split2(a1.x, a1.y, h.z, lo4.z);
                split2(a1.z, a1.w, h.w, lo4.w);
                bhi[rt][s] = as_bf16x8(h);
                blo[rt][s] = as_bf16x8(lo4);
            } else {
                const long o = rc * (HID / 2) + s * 16 + q * 4;
                bhi[rt][s] = as_bf16x8(*(const uint4*)(Xhi + o));
                blo[rt][s] = as_bf16x8(*(const uint4*)(Xlo + o));
            }
        }
    }

    f32x4 acc[2][8];
#pragma unroll
    for (int rt = 0; rt < 2; ++rt)
#pragma unroll
        for (int t = 0; t < 8; ++t) acc[rt][t] = (f32x4)0.0f;

#pragma unroll
    for (int s = 0; s < 4; ++s) {
#pragma unroll
        for (int t = 0; t < 8; ++t) {
            const int fo = ((s * 8 + t) * 64 + l) * 4;
            const bf16x8 whi = as_bf16x8(*(const uint4*)(Wphi + fo));
            const bf16x8 wlo = as_bf16x8(*(const uint4*)(Wplo + fo));
#pragma unroll
            for (int rt = 0; rt < 2; ++rt) {
                acc[rt][t] = __builtin_amdgcn_mfma_f32_16x16x32_bf16(whi, bhi[rt][s], acc[rt][t], 0, 0, 0);
                acc[rt][t] = __builtin_amdgcn_mfma_f32_16x16x32_bf16(whi, blo[rt][s], acc[rt][t], 0, 0, 0);
                acc[rt][t] = __builtin_amdgcn_mfma_f32_16x16x32_bf16(wlo, bhi[rt][s], acc[rt][t], 0, 0, 0);
            }
        }
    }

#pragma unroll
    for (int rt = 0; rt < 2; ++rt) {
        const long row = rowbase + rt * 16 + cm;
        if (row < N) {
#pragma unroll
            for (int t = 0; t < 8; ++t) {
                uint2 o;
                o.x = pack2(acc[rt][t][0], acc[rt][t][1]);
                o.y = pack2(acc[rt][t][2], acc[rt][t][3]);
                *(uint2*)&HS[row * HID + t * 16 + q * 4] = o;
            }
        }
    }
}

// fat: gemm1 || bucket histogram (LDS-aggregated, 391 global atomics/block)
__global__ __launch_bounds__(256) void gemm1_hist_kernel(
        const float* __restrict__ emb, const uint* __restrict__ Wphi,
        const uint* __restrict__ Wplo, ushort* __restrict__ HS, int N,
        const int* __restrict__ dst, int* __restrict__ bcnt, int E, int GB, int NB) {
    __shared__ int h[400];
    if ((int)blockIdx.x < GB) {
        gemm_body_mfma<true>(emb, nullptr, nullptr, Wphi, Wplo, HS, N, blockIdx.x, threadIdx.x);
    } else {
        const int hb = blockIdx.x - GB;
        const int nblk = gridDim.x - GB;
        const int ech = (E + nblk - 1) / nblk;
        const int e0 = hb * ech;
        const int e1 = min(E, e0 + ech);
        for (int i = threadIdx.x; i < NB; i += 256) h[i] = 0;
        __syncthreads();
        for (int e = e0 + (int)threadIdx.x; e < e1; e += 256) atomicAdd(&h[dst[e] >> 8], 1);
        __syncthreads();
        for (int i = threadIdx.x; i < NB; i += 256)
            if (h[i]) atomicAdd(&bcnt[i], h[i]);
    }
}

__global__ __launch_bounds__(256) void gemm2_kernel(
        const uint* __restrict__ Xhi, const uint* __restrict__ Xlo,
        const uint* __restrict__ Wphi, const uint* __restrict__ Wplo,
        ushort* __restrict__ HS, int N) {
    gemm_body_mfma<false>(nullptr, Xhi, Xlo, Wphi, Wplo, HS, N, blockIdx.x, threadIdx.x);
}

// ================================================================ bucket scan (391-wide)
__global__ __launch_bounds__(512) void scan_buckets_kernel(const int* __restrict__ bcnt,
                                                           int* bbase, int* gcursor, int NB, int E) {
    __shared__ int sh[512];
    const int t = threadIdx.x;
    const int v = (t < NB) ? bcnt[t] : 0;
    sh[t] = v;
    __syncthreads();
    for (int off = 1; off < 512; off <<= 1) {
        int x = (t >= off) ? sh[t - off] : 0;
        __syncthreads();
        sh[t] += x;
        __syncthreads();
    }
    const int excl = sh[t] - v;
    if (t < NB) { bbase[t] = excl; gcursor[t] = excl; }
    if (t == NB - 1) bbase[NB] = excl + v;
}

// ================================================================ partition by bucket (dst>>8)
__global__ __launch_bounds__(256) void partition_kernel(
        const int* __restrict__ src, const int* __restrict__ dst,
        int* __restrict__ gcursor, uint* __restrict__ staged, int E, int NB) {
    __shared__ int hist[400], lbase[400], loff[400];
    const int t = threadIdx.x;
    const int e0 = blockIdx.x * PCHUNK;
    for (int i = t; i < NB; i += 256) { hist[i] = 0; loff[i] = 0; }
    __syncthreads();
#pragma unroll
    for (int j = 0; j < PCHUNK / 256; ++j) {
        const int e = e0 + j * 256 + t;
        if (e < E) atomicAdd(&hist[dst[e] >> 8], 1);
    }
    __syncthreads();
    for (int b = t; b < NB; b += 256)
        if (hist[b] > 0) lbase[b] = atomicAdd(&gcursor[b], hist[b]);
    __syncthreads();
#pragma unroll
    for (int j = 0; j < PCHUNK / 256; ++j) {
        const int e = e0 + j * 256 + t;
        if (e < E) {
            const int d = dst[e];
            const int b = d >> 8;
            const int pos = lbase[b] + atomicAdd(&loff[b], 1);
            staged[pos] = (uint)src[e] | ((uint)(d & 255) << 17);
        }
    }
}

// ================================================================ fill: per-bucket deg/scan/invs/col
__global__ __launch_bounds__(256) void fill_bucket_kernel(
        const uint* __restrict__ staged, const int* __restrict__ bbase,
        int* __restrict__ rps, int* __restrict__ deg, float* __restrict__ invs,
        int* __restrict__ col, int N) {
    __shared__ int h[256], cur[256], sh[256];
    const int b = blockIdx.x, t = threadIdx.x;
    const int w0 = bbase[b], w1 = bbase[b + 1];
    const int base0 = b << 8;
    h[t] = 0;
    __syncthreads();
    for (int i = w0 + t; i < w1; i += 256) atomicAdd(&h[staged[i] >> 17], 1);
    __syncthreads();
    const int my = h[t];
    sh[t] = my;
    __syncthreads();
    for (int off = 1; off < 256; off <<= 1) {
        int x = (t >= off) ? sh[t - off] : 0;
        __syncthreads();
        sh[t] += x;
        __syncthreads();
    }
    const int start = w0 + sh[t] - my;
    cur[t] = start;
    const int node = base0 + t;
    if (node < N) {
        deg[node] = my;
        rps[node] = start;
        invs[node] = rsqrtf((float)my + 1.0f);
    }
    __syncthreads();
    for (int i = w0 + t; i < w1; i += 256) {
        const uint u = staged[i];
        const int p = atomicAdd(&cur[u >> 17], 1);
        col[p] = (int)(u & 0x1FFFFu);
    }
}

// ================================================================ pull1: agg + relu -> X1' = invs*relu(...) (hi/lo)
// 8 lanes/node; lane holds 16 features (2 x uint4). Batch-4 gathers for MLP.
__global__ __launch_bounds__(256) void pull_relu_kernel(
        const int* __restrict__ rps, const int* __restrict__ deg, const int* __restrict__ col,
        const uint* __restrict__ HS, const float* __restrict__ invs,
        const float* __restrict__ b, uint* __restrict__ Xhi, uint* __restrict__ Xlo, int N) {
    const int g = blockIdx.x * 256 + threadIdx.x;
    const int node = g >> 3;
    if (node >= N) return;
    const int lane = g & 7;
    const int d = deg[node];
    const int p = rps[node];
    const uint4* H4 = (const uint4*)HS;
    const size_t so = (size_t)node * 16 + lane * 2;

    float acc[16];
    {
        const float sn = invs[node];
        float f[16];
        unpack8(H4[so], f);
        unpack8(H4[so + 1], f + 8);
#pragma unroll
        for (int j = 0; j < 16; ++j) acc[j] = f[j] * sn;
    }
    int i = 0;
    for (; i + 4 <= d; i += 4) {
        const int s0 = col[p + i], s1 = col[p + i + 1], s2 = col[p + i + 2], s3 = col[p + i + 3];
        const float w0 = invs[s0], w1 = invs[s1], w2 = invs[s2], w3 = invs[s3];
        const uint4 a0 = H4[(size_t)s0 * 16 + lane * 2], a0b = H4[(size_t)s0 * 16 + lane * 2 + 1];
        const uint4 a1 = H4[(size_t)s1 * 16 + lane * 2], a1b = H4[(size_t)s1 * 16 + lane * 2 + 1];
        const uint4 a2 = H4[(size_t)s2 * 16 + lane * 2], a2b = H4[(size_t)s2 * 16 + lane * 2 + 1];
        const uint4 a3 = H4[(size_t)s3 * 16 + lane * 2], a3b = H4[(size_t)s3 * 16 + lane * 2 + 1];
        float f[16];
        unpack8(a0, f); unpack8(a0b, f + 8);
#pragma unroll
        for (int j = 0; j < 16; ++j) acc[j] += f[j] * w0;
        unpack8(a1, f); unpack8(a1b, f + 8);
#pragma unroll
        for (int j = 0; j < 16; ++j) acc[j] += f[j] * w1;
        unpack8(a2, f); unpack8(a2b, f + 8);
#pragma unroll
        for (int j = 0; j < 16; ++j) acc[j] += f[j] * w2;
        unpack8(a3, f); unpack8(a3b, f + 8);
#pragma unroll
        for (int j = 0; j < 16; ++j) acc[j] += f[j] * w3;
    }
    for (; i < d; ++i) {
        const int s0 = col[p + i];
        const float w0 = invs[s0];
        const uint4 a0 = H4[(size_t)s0 * 16 + lane * 2], a0b = H4[(size_t)s0 * 16 + lane * 2 + 1];
        float f[16];
        unpack8(a0, f); unpack8(a0b, f + 8);
#pragma unroll
        for (int j = 0; j < 16; ++j) acc[j] += f[j] * w0;
    }
    const float sn = invs[node];
    float x[16];
#pragma unroll
    for (int j = 0; j < 16; ++j)
        x[j] = sn * fmaxf(acc[j] * sn + b[lane * 16 + j], 0.0f);  // pre-scaled X1'
    uint4 h0, l0, h1, l1;
    split2(x[0], x[1], h0.x, l0.x);   split2(x[2], x[3], h0.y, l0.y);
    split2(x[4], x[5], h0.z, l0.z);   split2(x[6], x[7], h0.w, l0.w);
    split2(x[8], x[9], h1.x, l1.x);   split2(x[10], x[11], h1.y, l1.y);
    split2(x[12], x[13], h1.z, l1.z); split2(x[14], x[15], h1.w, l1.w);
    uint* oh = Xhi + (size_t)node * 64 + lane * 8;
    uint* ol = Xlo + (size_t)node * 64 + lane * 8;
    *(uint4*)oh = h0; *(uint4*)(oh + 4) = h1;
    *(uint4*)ol = l0; *(uint4*)(ol + 4) = l1;
}

// ================================================================ pull2 + relu + out-GEMM (128->10)
// HS here = H2' (rows pre-scaled by invs[src]); no per-edge invs needed.
// W_out swizzled in LDS as float4 slots [(c*4+j')*8 + lane] -> conflict-free broadcast reads.
__global__ __launch_bounds__(256) void pull_out_kernel(
        const int* __restrict__ rps, const int* __restrict__ deg, const int* __restrict__ col,
        const uint* __restrict__ HS, const float* __restrict__ invs,
        const float* __restrict__ b2, const float* __restrict__ Wout,
        const float* __restrict__ bout, float* __restrict__ OUT, int N) {
    __shared__ float Wd[320 * 4];
    for (int t = threadIdx.x; t < 320; t += 256) {
        const int c = t >> 5, rem = t & 31, j4 = rem >> 3, l = rem & 7;
        const int k0 = l * 16 + j4 * 4;
        float4 w;
        w.x = Wout[(k0 + 0) * NCLASS + c];
        w.y = Wout[(k0 + 1) * NCLASS + c];
        w.z = Wout[(k0 + 2) * NCLASS + c];
        w.w = Wout[(k0 + 3) * NCLASS + c];
        ((float4*)Wd)[t] = w;
    }
    __syncthreads();

    const int g = blockIdx.x * 256 + threadIdx.x;
    const int node = g >> 3;
    if (node >= N) return;
    const int lane = g & 7;
    const int d = deg[node];
    const int p = rps[node];
    const uint4* H4 = (const uint4*)HS;
    const size_t so = (size_t)node * 16 + lane * 2;

    float acc[16];
    {
        float f[16];
        unpack8(H4[so], f);
        unpack8(H4[so + 1], f + 8);
#pragma unroll
        for (int j = 0; j < 16; ++j) acc[j] = f[j];  // self-loop (already invs-scaled)
    }
    int i = 0;
    for (; i + 4 <= d; i += 4) {
        const int s0 = col[p + i], s1 = col[p + i + 1], s2 = col[p + i + 2], s3 = col[p + i + 3];
        const uint4 a0 = H4[(size_t)s0 * 16 + lane * 2], a0b = H4[(size_t)s0 * 16 + lane * 2 + 1];
        const uint4 a1 = H4[(size_t)s1 * 16 + lane * 2], a1b = H4[(size_t)s1 * 16 + lane * 2 + 1];
        const uint4 a2 = H4[(size_t)s2 * 16 + lane * 2], a2b = H4[(size_t)s2 * 16 + lane * 2 + 1];
        const uint4 a3 = H4[(size_t)s3 * 16 + lane * 2], a3b = H4[(size_t)s3 * 16 + lane * 2 + 1];
        float f[16];
        unpack8(a0, f); unpack8(a0b, f + 8);
#pragma unroll
        for (int j = 0; j < 16; ++j) acc[j] += f[j];
        unpack8(a1, f); unpack8(a1b, f + 8);
#pragma unroll
        for (int j = 0; j < 16; ++j) acc[j] += f[j];
        unpack8(a2, f); unpack8(a2b, f + 8);
#pragma unroll
        for (int j = 0; j < 16; ++j) acc[j] += f[j];
        unpack8(a3, f); unpack8(a3b, f + 8);
#pragma unroll
        for (int j = 0; j < 16; ++j) acc[j] += f[j];
    }
    for (; i < d; ++i) {
        const int s0 = col[p + i];
        const uint4 a0 = H4[(size_t)s0 * 16 + lane * 2], a0b = H4[(size_t)s0 * 16 + lane * 2 + 1];
        float f[16];
        unpack8(a0, f); unpack8(a0b, f + 8);
#pragma unroll
        for (int j = 0; j < 16; ++j) acc[j] += f[j];
    }
    const float sn = invs[node];
    float x[16];
#pragma unroll
    for (int j = 0; j < 16; ++j) x[j] = fmaxf(acc[j] * sn + b2[lane * 16 + j], 0.0f);

    const float4 xv0 = make_float4(x[0], x[1], x[2], x[3]);
    const float4 xv1 = make_float4(x[4], x[5], x[6], x[7]);
    const float4 xv2 = make_float4(x[8], x[9], x[10], x[11]);
    const float4 xv3 = make_float4(x[12], x[13], x[14], x[15]);
    const float4* Wd4 = (const float4*)Wd;
#pragma unroll
    for (int c = 0; c < NCLASS; ++c) {
        const float4* wp = Wd4 + c * 32 + lane;
        const float4 w0 = wp[0], w1 = wp[8], w2 = wp[16], w3 = wp[24];
        float s = xv0.x * w0.x + xv0.y * w0.y + xv0.z * w0.z + xv0.w * w0.w
                + xv1.x * w1.x + xv1.y * w1.y + xv1.z * w1.z + xv1.w * w1.w
                + xv2.x * w2.x + xv2.y * w2.y + xv2.z * w2.z + xv2.w * w2.w
                + xv3.x * w3.x + xv3.y * w3.y + xv3.z * w3.z + xv3.w * w3.w;
        s += __shfl_xor(s, 1, 8);
        s += __shfl_xor(s, 2, 8);
        s += __shfl_xor(s, 4, 8);
        if (lane == (c & 7)) OUT[(size_t)node * NCLASS + c] = s + bout[c];
    }
}

// ================================================================ launch
extern "C" void kernel_launch(void* const* d_in, const int* in_sizes, int n_in,
                              void* d_out, int out_size, void* d_ws, size_t ws_size,
                              hipStream_t stream) {
    const int* ei     = (const int*)d_in[0];
    const float* emb  = (const float*)d_in[1];
    const float* W1   = (const float*)d_in[2];
    const float* b1   = (const float*)d_in[3];
    const float* W2   = (const float*)d_in[4];
    const float* b2   = (const float*)d_in[5];
    const float* Wout = (const float*)d_in[6];
    const float* bout = (const float*)d_in[7];
    float* out        = (float*)d_out;

    const int E = in_sizes[0] / 2;
    const int N = in_sizes[1] / HID;
    const int* src = ei;
    const int* dst = ei + E;
    (void)ws_size; (void)n_in; (void)out_size;

    const int GB = (N + 127) / 128;      // 782 gemm blocks
    const int NB = (N + 255) >> 8;       // 391 buckets
    const int PB = (E + PCHUNK - 1) / PCHUNK;

    char* ws = (char*)d_ws;
    size_t off = 0;
    auto alloc = [&](size_t bytes) {
        void* p = ws + off;
        off = (off + bytes + 4095) & ~(size_t)4095;
        return p;
    };
    int*   bcnt    = (int*)alloc(512 * 4);
    int*   bbase   = (int*)alloc(512 * 4);
    int*   gcursor = (int*)alloc(512 * 4);
    int*   deg     = (int*)alloc((size_t)N * 4);
    int*   rps     = (int*)alloc((size_t)N * 4);
    float* invs    = (float*)alloc((size_t)N * 4);
    int*   col     = (int*)alloc((size_t)E * 4);
    uint*  staged  = (uint*)alloc((size_t)E * 4);
    uint*  Wp1hi   = (uint*)alloc(HID * HID * 2);
    uint*  Wp1lo   = (uint*)alloc(HID * HID * 2);
    uint*  Wp2hi   = (uint*)alloc(HID * HID * 2);
    uint*  Wp2lo   = (uint*)alloc(HID * HID * 2);
    uint*  HS      = (uint*)alloc((size_t)N * HID * 2);  // bf16 features (both layers)
    uint*  X1hi    = (uint*)alloc((size_t)N * HID * 2);
    uint*  X1lo    = (uint*)alloc((size_t)N * HID * 2);

    pack_w_kernel<<<32, 64, 0, stream>>>(W1, Wp1hi, Wp1lo);
    pack_w_kernel<<<32, 64, 0, stream>>>(W2, Wp2hi, Wp2lo);

    hipMemsetAsync(bcnt, 0, 512 * 4, stream);
    // gemm1 (emb@W1 -> HS1 bf16) || bucket histogram
    gemm1_hist_kernel<<<GB + HB, 256, 0, stream>>>(emb, Wp1hi, Wp1lo, (ushort*)HS, N,
                                                   dst, bcnt, E, GB, NB);
    scan_buckets_kernel<<<1, 512, 0, stream>>>(bcnt, bbase, gcursor, NB, E);
    partition_kernel<<<PB, 256, 0, stream>>>(src, dst, gcursor, staged, E, NB);
    fill_bucket_kernel<<<NB, 256, 0, stream>>>(staged, bbase, rps, deg, invs, col, N);

    // layer 1 aggregate -> X1' = invs * relu(...) (hi/lo planes)
    pull_relu_kernel<<<(N * 8 + 255) / 256, 256, 0, stream>>>(
        rps, deg, col, HS, invs, b1, X1hi, X1lo, N);

    // layer 2: H2' = X1'@W2 (rows already invs-scaled), then fused pull+relu+out-GEMM
    gemm2_kernel<<<GB, 256, 0, stream>>>(X1hi, X1lo, Wp2hi, Wp2lo, (ushort*)HS, N);
    pull_out_kernel<<<(N * 8 + 255) / 256, 256, 0, stream>>>(
        rps, deg, col, HS, invs, b2, Wout, bout, out, N);
}

// Round 7
// 337.002 us; speedup vs baseline: 17.4816x; 1.0620x over previous
//
#include <hip/hip_runtime.h>
#include <hip/hip_bf16.h>

#define HID 128
#define NCLASS 10
#define PCHUNK 8192
#define HB 256  // hist partner blocks

typedef unsigned int uint;
typedef unsigned short ushort;
typedef __attribute__((ext_vector_type(8))) __bf16 bf16x8;
typedef __attribute__((ext_vector_type(4))) float f32x4;

// ---- bf16 helpers -----------------------------------------------------------
__device__ __forceinline__ uint bf16rne(float x) {
    uint u = __float_as_uint(x);
    return (u + 0x7FFFu + ((u >> 16) & 1u)) >> 16;
}
__device__ __forceinline__ uint pack2(float e0, float e1) {
    return bf16rne(e0) | (bf16rne(e1) << 16);
}
__device__ __forceinline__ void unpack2(uint w, float& lo, float& hi) {
    lo = __uint_as_float(w << 16);
    hi = __uint_as_float(w & 0xFFFF0000u);
}
__device__ __forceinline__ void split2(float e0, float e1, uint& h, uint& l) {
    uint h0 = bf16rne(e0), h1 = bf16rne(e1);
    float r0 = e0 - __uint_as_float(h0 << 16);
    float r1 = e1 - __uint_as_float(h1 << 16);
    h = h0 | (h1 << 16);
    l = bf16rne(r0) | (bf16rne(r1) << 16);
}
__device__ __forceinline__ bf16x8 as_bf16x8(uint4 u) {
    return __builtin_bit_cast(bf16x8, u);
}
__device__ __forceinline__ void unpack8(uint4 u, float* f) {
    unpack2(u.x, f[0], f[1]); unpack2(u.y, f[2], f[3]);
    unpack2(u.z, f[4], f[5]); unpack2(u.w, f[6], f[7]);
}

// ---- W pre-pack device body (fragment order, hi/lo planes) ------------------
__device__ __forceinline__ void pack_w_body(const float* __restrict__ W,
                                            uint* __restrict__ hi, uint* __restrict__ lo,
                                            int slot, int l) {
    const int s = slot >> 3, t = slot & 7;
    const int kb = s * 32 + (l >> 4) * 8, n = t * 16 + (l & 15);
    float f[8];
#pragma unroll
    for (int j = 0; j < 8; ++j) f[j] = W[(kb + j) * HID + n];
    uint4 h, lo4;
    split2(f[0], f[1], h.x, lo4.x);
    split2(f[2], f[3], h.y, lo4.y);
    split2(f[4], f[5], h.z, lo4.z);
    split2(f[6], f[7], h.w, lo4.w);
    const int fo = (slot * 64 + l) * 4;
    *(uint4*)(hi + fo) = h;
    *(uint4*)(lo + fo) = lo4;
}

// fat: bucket histogram (blocks 0..HB-1) || pack W1 (HB..HB+7) || pack W2 (HB+8..HB+15)
__global__ __launch_bounds__(256) void hist_pack_kernel(
        const int* __restrict__ dst, int* __restrict__ bcnt, int E, int NB,
        const float* __restrict__ W1, uint* __restrict__ W1hi, uint* __restrict__ W1lo,
        const float* __restrict__ W2, uint* __restrict__ W2hi, uint* __restrict__ W2lo) {
    __shared__ int h[400];
    const int t = threadIdx.x;
    if ((int)blockIdx.x < HB) {
        const int ech = (E + HB - 1) / HB;
        const int e0 = blockIdx.x * ech;
        const int e1 = min(E, e0 + ech);
        for (int i = t; i < NB; i += 256) h[i] = 0;
        __syncthreads();
        for (int e = e0 + t; e < e1; e += 256) atomicAdd(&h[dst[e] >> 8], 1);
        __syncthreads();
        for (int i = t; i < NB; i += 256)
            if (h[i]) atomicAdd(&bcnt[i], h[i]);
    } else {
        const int pb = blockIdx.x - HB;
        const int slot = (pb & 7) * 4 + (t >> 6);
        const int l = t & 63;
        if (pb < 8) pack_w_body(W1, W1hi, W1lo, slot, l);
        else        pack_w_body(W2, W2hi, W2lo, slot, l);
    }
}

// ================================================================ MFMA GEMM (A=W, B=X)
// FP32IN: X fp32, 3-term split product. else: X = single bf16 hi plane, 2-term.
template <bool FP32IN>
__device__ __forceinline__ void gemm_body_mfma(
        const float* __restrict__ Xf, const uint* __restrict__ Xhi,
        const uint* __restrict__ Wphi, const uint* __restrict__ Wplo,
        ushort* __restrict__ HS, int N, int bidx, int tid) {
    const int wv = tid >> 6;
    const int l = tid & 63;
    const int q = l >> 4;
    const int cm = l & 15;
    const long rowbase = (long)bidx * 128 + wv * 32;

    bf16x8 bhi[2][4], blo[2][4];
#pragma unroll
    for (int rt = 0; rt < 2; ++rt) {
        const long row = rowbase + rt * 16 + cm;
        const long rc = row < N ? row : (N - 1);
#pragma unroll
        for (int s = 0; s < 4; ++s) {
            if (FP32IN) {
                const float* xp = Xf + rc * HID + s * 32 + q * 8;
                const float4 a0 = ((const float4*)xp)[0];
                const float4 a1 = ((const float4*)xp)[1];
                uint4 h, lo4;
                split2(a0.x, a0.y, h.x, lo4.x);
                split2(a0.z, a0.w, h.y, lo4.y);
                split2(a1.x, a1.y, h.z, lo4.z);
                split2(a1.z, a1.w, h.w, lo4.w);
                bhi[rt][s] = as_bf16x8(h);
                blo[rt][s] = as_bf16x8(lo4);
            } else {
                const long o = rc * (HID / 2) + s * 16 + q * 4;
                bhi[rt][s] = as_bf16x8(*(const uint4*)(Xhi + o));
            }
        }
    }

    f32x4 acc[2][8];
#pragma unroll
    for (int rt = 0; rt < 2; ++rt)
#pragma unroll
        for (int t = 0; t < 8; ++t) acc[rt][t] = (f32x4)0.0f;

#pragma unroll
    for (int s = 0; s < 4; ++s) {
#pragma unroll
        for (int t = 0; t < 8; ++t) {
            const int fo = ((s * 8 + t) * 64 + l) * 4;
            const bf16x8 whi = as_bf16x8(*(const uint4*)(Wphi + fo));
            const bf16x8 wlo = as_bf16x8(*(const uint4*)(Wplo + fo));
#pragma unroll
            for (int rt = 0; rt < 2; ++rt) {
                acc[rt][t] = __builtin_amdgcn_mfma_f32_16x16x32_bf16(whi, bhi[rt][s], acc[rt][t], 0, 0, 0);
                if (FP32IN)
                    acc[rt][t] = __builtin_amdgcn_mfma_f32_16x16x32_bf16(whi, blo[rt][s], acc[rt][t], 0, 0, 0);
                acc[rt][t] = __builtin_amdgcn_mfma_f32_16x16x32_bf16(wlo, bhi[rt][s], acc[rt][t], 0, 0, 0);
            }
        }
    }

#pragma unroll
    for (int rt = 0; rt < 2; ++rt) {
        const long row = rowbase + rt * 16 + cm;
        if (row < N) {
#pragma unroll
            for (int t = 0; t < 8; ++t) {
                uint2 o;
                o.x = pack2(acc[rt][t][0], acc[rt][t][1]);
                o.y = pack2(acc[rt][t][2], acc[rt][t][3]);
                *(uint2*)&HS[row * HID + t * 16 + q * 4] = o;
            }
        }
    }
}

// fat: partition (blocks 0..PB-1, starts immediately) || gemm1 (PB..PB+GB-1)
__global__ __launch_bounds__(256) void gemm1_part_kernel(
        const float* __restrict__ emb, const uint* __restrict__ Wphi,
        const uint* __restrict__ Wplo, ushort* __restrict__ HS, int N,
        const int* __restrict__ src, const int* __restrict__ dst,
        int* __restrict__ gcursor, uint* __restrict__ staged, int E, int PB, int NB) {
    __shared__ int hist[400], lbase[400], loff[400];
    const int t = threadIdx.x;
    if ((int)blockIdx.x >= PB) {
        gemm_body_mfma<true>(emb, nullptr, Wphi, Wplo, HS, N, blockIdx.x - PB, t);
        return;
    }
    const int e0 = blockIdx.x * PCHUNK;
    for (int i = t; i < NB; i += 256) { hist[i] = 0; loff[i] = 0; }
    __syncthreads();
#pragma unroll
    for (int j = 0; j < PCHUNK / 256; ++j) {
        const int e = e0 + j * 256 + t;
        if (e < E) atomicAdd(&hist[dst[e] >> 8], 1);
    }
    __syncthreads();
    for (int b = t; b < NB; b += 256)
        if (hist[b] > 0) lbase[b] = atomicAdd(&gcursor[b], hist[b]);
    __syncthreads();
#pragma unroll
    for (int j = 0; j < PCHUNK / 256; ++j) {
        const int e = e0 + j * 256 + t;
        if (e < E) {
            const int d = dst[e];
            const int b = d >> 8;
            const int pos = lbase[b] + atomicAdd(&loff[b], 1);
            staged[pos] = (uint)src[e] | ((uint)(d & 255) << 17);
        }
    }
}

__global__ __launch_bounds__(256) void gemm2_kernel(
        const uint* __restrict__ Xhi, const uint* __restrict__ Wphi,
        const uint* __restrict__ Wplo, ushort* __restrict__ HS, int N) {
    gemm_body_mfma<false>(nullptr, Xhi, Wphi, Wplo, HS, N, blockIdx.x, threadIdx.x);
}

// ================================================================ bucket scan (writes rps[N]=E sentinel)
__global__ __launch_bounds__(512) void scan_buckets_kernel(const int* __restrict__ bcnt,
                                                           int* bbase, int* gcursor,
                                                           int* rps, int NB, int E, int N) {
    __shared__ int sh[512];
    const int t = threadIdx.x;
    const int v = (t < NB) ? bcnt[t] : 0;
    sh[t] = v;
    __syncthreads();
    for (int off = 1; off < 512; off <<= 1) {
        int x = (t >= off) ? sh[t - off] : 0;
        __syncthreads();
        sh[t] += x;
        __syncthreads();
    }
    const int excl = sh[t] - v;
    if (t < NB) { bbase[t] = excl; gcursor[t] = excl; }
    if (t == NB - 1) bbase[NB] = excl + v;
    if (t == 0) rps[N] = E;
}

// ================================================================ fill: per-bucket deg/scan/invs/col
__global__ __launch_bounds__(256) void fill_bucket_kernel(
        const uint* __restrict__ staged, const int* __restrict__ bbase,
        int* __restrict__ rps, float* __restrict__ invs, int* __restrict__ col, int N) {
    __shared__ int h[256], cur[256], sh[256];
    const int b = blockIdx.x, t = threadIdx.x;
    const int w0 = bbase[b], w1 = bbase[b + 1];
    const int base0 = b << 8;
    h[t] = 0;
    __syncthreads();
    for (int i = w0 + t; i < w1; i += 256) atomicAdd(&h[staged[i] >> 17], 1);
    __syncthreads();
    const int my = h[t];
    sh[t] = my;
    __syncthreads();
    for (int off = 1; off < 256; off <<= 1) {
        int x = (t >= off) ? sh[t - off] : 0;
        __syncthreads();
        sh[t] += x;
        __syncthreads();
    }
    const int start = w0 + sh[t] - my;
    cur[t] = start;
    const int node = base0 + t;
    if (node < N) {
        rps[node] = start;
        invs[node] = rsqrtf((float)my + 1.0f);
    }
    __syncthreads();
    for (int i = w0 + t; i < w1; i += 256) {
        const uint u = staged[i];
        const int p = atomicAdd(&cur[u >> 17], 1);
        col[p] = (int)(u & 0x1FFFFu);
    }
}

// ================================================================ pull1: agg + relu -> X1' = invs*relu(...) (bf16 hi only)
// 8 lanes/node; lane holds 16 features (2 x uint4). Batch-4 gathers.
__global__ __launch_bounds__(256) void pull_relu_kernel(
        const int* __restrict__ rps, const int* __restrict__ col,
        const uint* __restrict__ HS, const float* __restrict__ invs,
        const float* __restrict__ b, uint* __restrict__ Xhi, int N) {
    const int g = blockIdx.x * 256 + threadIdx.x;
    const int node = g >> 3;
    if (node >= N) return;
    const int lane = g & 7;
    const int p = rps[node];
    const int d = rps[node + 1] - p;
    const uint4* H4 = (const uint4*)HS;
    const size_t so = (size_t)node * 16 + lane * 2;

    float acc[16];
    {
        const float sn = invs[node];
        float f[16];
        unpack8(H4[so], f);
        unpack8(H4[so + 1], f + 8);
#pragma unroll
        for (int j = 0; j < 16; ++j) acc[j] = f[j] * sn;
    }
    int i = 0;
    for (; i + 4 <= d; i += 4) {
        const int s0 = col[p + i], s1 = col[p + i + 1], s2 = col[p + i + 2], s3 = col[p + i + 3];
        const float w0 = invs[s0], w1 = invs[s1], w2 = invs[s2], w3 = invs[s3];
        const uint4 a0 = H4[(size_t)s0 * 16 + lane * 2], a0b = H4[(size_t)s0 * 16 + lane * 2 + 1];
        const uint4 a1 = H4[(size_t)s1 * 16 + lane * 2], a1b = H4[(size_t)s1 * 16 + lane * 2 + 1];
        const uint4 a2 = H4[(size_t)s2 * 16 + lane * 2], a2b = H4[(size_t)s2 * 16 + lane * 2 + 1];
        const uint4 a3 = H4[(size_t)s3 * 16 + lane * 2], a3b = H4[(size_t)s3 * 16 + lane * 2 + 1];
        float f[16];
        unpack8(a0, f); unpack8(a0b, f + 8);
#pragma unroll
        for (int j = 0; j < 16; ++j) acc[j] += f[j] * w0;
        unpack8(a1, f); unpack8(a1b, f + 8);
#pragma unroll
        for (int j = 0; j < 16; ++j) acc[j] += f[j] * w1;
        unpack8(a2, f); unpack8(a2b, f + 8);
#pragma unroll
        for (int j = 0; j < 16; ++j) acc[j] += f[j] * w2;
        unpack8(a3, f); unpack8(a3b, f + 8);
#pragma unroll
        for (int j = 0; j < 16; ++j) acc[j] += f[j] * w3;
    }
    for (; i < d; ++i) {
        const int s0 = col[p + i];
        const float w0 = invs[s0];
        const uint4 a0 = H4[(size_t)s0 * 16 + lane * 2], a0b = H4[(size_t)s0 * 16 + lane * 2 + 1];
        float f[16];
        unpack8(a0, f); unpack8(a0b, f + 8);
#pragma unroll
        for (int j = 0; j < 16; ++j) acc[j] += f[j] * w0;
    }
    const float sn = invs[node];
    float x[16];
#pragma unroll
    for (int j = 0; j < 16; ++j)
        x[j] = sn * fmaxf(acc[j] * sn + b[lane * 16 + j], 0.0f);  // pre-scaled X1'
    uint4 h0, h1;
    h0.x = pack2(x[0], x[1]);   h0.y = pack2(x[2], x[3]);
    h0.z = pack2(x[4], x[5]);   h0.w = pack2(x[6], x[7]);
    h1.x = pack2(x[8], x[9]);   h1.y = pack2(x[10], x[11]);
    h1.z = pack2(x[12], x[13]); h1.w = pack2(x[14], x[15]);
    uint* oh = Xhi + (size_t)node * 64 + lane * 8;
    *(uint4*)oh = h0; *(uint4*)(oh + 4) = h1;
}

// ================================================================ pull2 + relu + out-GEMM (128->10)
// HS here = H2' (rows pre-scaled by invs[src]); W_out swizzled conflict-free in LDS.
__global__ __launch_bounds__(256) void pull_out_kernel(
        const int* __restrict__ rps, const int* __restrict__ col,
        const uint* __restrict__ HS, const float* __restrict__ invs,
        const float* __restrict__ b2, const float* __restrict__ Wout,
        const float* __restrict__ bout, float* __restrict__ OUT, int N) {
    __shared__ float Wd[320 * 4];
    for (int t = threadIdx.x; t < 320; t += 256) {
        const int c = t >> 5, rem = t & 31, j4 = rem >> 3, l = rem & 7;
        const int k0 = l * 16 + j4 * 4;
        float4 w;
        w.x = Wout[(k0 + 0) * NCLASS + c];
        w.y = Wout[(k0 + 1) * NCLASS + c];
        w.z = Wout[(k0 + 2) * NCLASS + c];
        w.w = Wout[(k0 + 3) * NCLASS + c];
        ((float4*)Wd)[t] = w;
    }
    __syncthreads();

    const int g = blockIdx.x * 256 + threadIdx.x;
    const int node = g >> 3;
    if (node >= N) return;
    const int lane = g & 7;
    const int p = rps[node];
    const int d = rps[node + 1] - p;
    const uint4* H4 = (const uint4*)HS;
    const size_t so = (size_t)node * 16 + lane * 2;

    float acc[16];
    {
        float f[16];
        unpack8(H4[so], f);
        unpack8(H4[so + 1], f + 8);
#pragma unroll
        for (int j = 0; j < 16; ++j) acc[j] = f[j];  // self-loop (already invs-scaled)
    }
    int i = 0;
    for (; i + 4 <= d; i += 4) {
        const int s0 = col[p + i], s1 = col[p + i + 1], s2 = col[p + i + 2], s3 = col[p + i + 3];
        const uint4 a0 = H4[(size_t)s0 * 16 + lane * 2], a0b = H4[(size_t)s0 * 16 + lane * 2 + 1];
        const uint4 a1 = H4[(size_t)s1 * 16 + lane * 2], a1b = H4[(size_t)s1 * 16 + lane * 2 + 1];
        const uint4 a2 = H4[(size_t)s2 * 16 + lane * 2], a2b = H4[(size_t)s2 * 16 + lane * 2 + 1];
        const uint4 a3 = H4[(size_t)s3 * 16 + lane * 2], a3b = H4[(size_t)s3 * 16 + lane * 2 + 1];
        float f[16];
        unpack8(a0, f); unpack8(a0b, f + 8);
#pragma unroll
        for (int j = 0; j < 16; ++j) acc[j] += f[j];
        unpack8(a1, f); unpack8(a1b, f + 8);
#pragma unroll
        for (int j = 0; j < 16; ++j) acc[j] += f[j];
        unpack8(a2, f); unpack8(a2b, f + 8);
#pragma unroll
        for (int j = 0; j < 16; ++j) acc[j] += f[j];
        unpack8(a3, f); unpack8(a3b, f + 8);
#pragma unroll
        for (int j = 0; j < 16; ++j) acc[j] += f[j];
    }
    for (; i < d; ++i) {
        const int s0 = col[p + i];
        const uint4 a0 = H4[(size_t)s0 * 16 + lane * 2], a0b = H4[(size_t)s0 * 16 + lane * 2 + 1];
        float f[16];
        unpack8(a0, f); unpack8(a0b, f + 8);
#pragma unroll
        for (int j = 0; j < 16; ++j) acc[j] += f[j];
    }
    const float sn = invs[node];
    float x[16];
#pragma unroll
    for (int j = 0; j < 16; ++j) x[j] = fmaxf(acc[j] * sn + b2[lane * 16 + j], 0.0f);

    const float4 xv0 = make_float4(x[0], x[1], x[2], x[3]);
    const float4 xv1 = make_float4(x[4], x[5], x[6], x[7]);
    const float4 xv2 = make_float4(x[8], x[9], x[10], x[11]);
    const float4 xv3 = make_float4(x[12], x[13], x[14], x[15]);
    const float4* Wd4 = (const float4*)Wd;
#pragma unroll
    for (int c = 0; c < NCLASS; ++c) {
        const float4* wp = Wd4 + c * 32 + lane;
        const float4 w0 = wp[0], w1 = wp[8], w2 = wp[16], w3 = wp[24];
        float s = xv0.x * w0.x + xv0.y * w0.y + xv0.z * w0.z + xv0.w * w0.w
                + xv1.x * w1.x + xv1.y * w1.y + xv1.z * w1.z + xv1.w * w1.w
                + xv2.x * w2.x + xv2.y * w2.y + xv2.z * w2.z + xv2.w * w2.w
                + xv3.x * w3.x + xv3.y * w3.y + xv3.z * w3.z + xv3.w * w3.w;
        s += __shfl_xor(s, 1, 8);
        s += __shfl_xor(s, 2, 8);
        s += __shfl_xor(s, 4, 8);
        if (lane == (c & 7)) OUT[(size_t)node * NCLASS + c] = s + bout[c];
    }
}

// ================================================================ launch
extern "C" void kernel_launch(void* const* d_in, const int* in_sizes, int n_in,
                              void* d_out, int out_size, void* d_ws, size_t ws_size,
                              hipStream_t stream) {
    const int* ei     = (const int*)d_in[0];
    const float* emb  = (const float*)d_in[1];
    const float* W1   = (const float*)d_in[2];
    const float* b1   = (const float*)d_in[3];
    const float* W2   = (const float*)d_in[4];
    const float* b2   = (const float*)d_in[5];
    const float* Wout = (const float*)d_in[6];
    const float* bout = (const float*)d_in[7];
    float* out        = (float*)d_out;

    const int E = in_sizes[0] / 2;
    const int N = in_sizes[1] / HID;
    const int* src = ei;
    const int* dst = ei + E;
    (void)ws_size; (void)n_in; (void)out_size;

    const int GB = (N + 127) / 128;      // 782 gemm blocks
    const int NB = (N + 255) >> 8;       // 391 buckets
    const int PB = (E + PCHUNK - 1) / PCHUNK;  // 196 partition blocks

    char* ws = (char*)d_ws;
    size_t off = 0;
    auto alloc = [&](size_t bytes) {
        void* p = ws + off;
        off = (off + bytes + 4095) & ~(size_t)4095;
        return p;
    };
    int*   bcnt    = (int*)alloc(512 * 4);
    int*   bbase   = (int*)alloc(512 * 4);
    int*   gcursor = (int*)alloc(512 * 4);
    int*   rps     = (int*)alloc((size_t)(N + 1) * 4);
    float* invs    = (float*)alloc((size_t)N * 4);
    int*   col     = (int*)alloc((size_t)E * 4);
    uint*  staged  = (uint*)alloc((size_t)E * 4);
    uint*  Wp1hi   = (uint*)alloc(HID * HID * 2);
    uint*  Wp1lo   = (uint*)alloc(HID * HID * 2);
    uint*  Wp2hi   = (uint*)alloc(HID * HID * 2);
    uint*  Wp2lo   = (uint*)alloc(HID * HID * 2);
    uint*  HS      = (uint*)alloc((size_t)N * HID * 2);  // bf16 features (both layers)
    uint*  X1hi    = (uint*)alloc((size_t)N * HID * 2);  // bf16 hidden (hi only)

    hipMemsetAsync(bcnt, 0, 512 * 4, stream);
    // bucket histogram || pack W1/W2
    hist_pack_kernel<<<HB + 16, 256, 0, stream>>>(dst, bcnt, E, NB,
                                                  W1, Wp1hi, Wp1lo, W2, Wp2hi, Wp2lo);
    scan_buckets_kernel<<<1, 512, 0, stream>>>(bcnt, bbase, gcursor, rps, NB, E, N);
    // partition (blocks 0..PB-1) || gemm1 emb@W1 -> HS1 bf16
    gemm1_part_kernel<<<PB + GB, 256, 0, stream>>>(emb, Wp1hi, Wp1lo, (ushort*)HS, N,
                                                   src, dst, gcursor, staged, E, PB, NB);
    fill_bucket_kernel<<<NB, 256, 0, stream>>>(staged, bbase, rps, invs, col, N);

    // layer 1 aggregate -> X1' = invs * relu(...) (bf16 hi plane only)
    pull_relu_kernel<<<(N * 8 + 255) / 256, 256, 0, stream>>>(
        rps, col, HS, invs, b1, X1hi, N);

    // layer 2: H2' = X1'@W2 (2-term), then fused pull+relu+out-GEMM
    gemm2_kernel<<<GB, 256, 0, stream>>>(X1hi, Wp2hi, Wp2lo, (ushort*)HS, N);
    pull_out_kernel<<<(N * 8 + 255) / 256, 256, 0, stream>>>(
        rps, col, HS, invs, b2, Wout, bout, out, N);
}